// Round 4
// baseline (1294.751 us; speedup 1.0000x reference)
//
#include <hip/hip_runtime.h>
#include <cstdint>
#include <cstddef>

typedef unsigned short u16;
typedef unsigned int   u32;
typedef __bf16 bf16x8 __attribute__((ext_vector_type(8)));
typedef float  f32x4  __attribute__((ext_vector_type(4)));

// ---------- bf16 helpers (RNE) ----------
__device__ __forceinline__ float bf2f(u16 u) {
  union { u32 i; float f; } v; v.i = ((u32)u) << 16; return v.f;
}
__device__ __forceinline__ u16 f2bf(float f) {
  union { float f; u32 i; } v; v.f = f;
  u32 r = v.i + 0x7fffu + ((v.i >> 16) & 1u);
  return (u16)(r >> 16);
}
__device__ __forceinline__ void unpack8(uint4 raw, float* v) {
  v[0]=bf2f(raw.x&0xffff); v[1]=bf2f(raw.x>>16);
  v[2]=bf2f(raw.y&0xffff); v[3]=bf2f(raw.y>>16);
  v[4]=bf2f(raw.z&0xffff); v[5]=bf2f(raw.z>>16);
  v[6]=bf2f(raw.w&0xffff); v[7]=bf2f(raw.w>>16);
}
__device__ __forceinline__ uint4 pack8(const float* v) {
  uint4 r;
  r.x = (u32)f2bf(v[0]) | ((u32)f2bf(v[1])<<16);
  r.y = (u32)f2bf(v[2]) | ((u32)f2bf(v[3])<<16);
  r.z = (u32)f2bf(v[4]) | ((u32)f2bf(v[5])<<16);
  r.w = (u32)f2bf(v[6]) | ((u32)f2bf(v[7])<<16);
  return r;
}
__device__ __forceinline__ void gload16(const void* g, void* l) {
  __builtin_amdgcn_global_load_lds((const __attribute__((address_space(1))) void*)g,
                                   (__attribute__((address_space(3))) void*)l, 16, 0, 0);
}
// attn LDS chunk swizzle: row-dependent XOR on the 16B-chunk index.
// Free on b128 reads (quarter-wave: 2 lanes/slot) AND on b32 V-writes.
__device__ __forceinline__ int swz8(int row) { return ((row >> 3) ^ row) & 7; }

// ---------- load 8 consecutive elems as f32, from f32 or bf16 source ----------
template<typename T>
__device__ __forceinline__ void load8(const T* p, float* v);
template<> __device__ __forceinline__ void load8<float>(const float* p, float* v) {
  const float4 a = ((const float4*)p)[0];
  const float4 b = ((const float4*)p)[1];
  v[0]=a.x; v[1]=a.y; v[2]=a.z; v[3]=a.w;
  v[4]=b.x; v[5]=b.y; v[6]=b.z; v[7]=b.w;
}
template<> __device__ __forceinline__ void load8<u16>(const u16* p, float* v) {
  unpack8(*(const uint4*)p, v);
}

// ---------- int32 (|q|<=127) -> bf16, EXACT (high-16 truncation of f32) ----------
__global__ __launch_bounds__(256) void cvt_k(const int* __restrict__ Q, u16* __restrict__ W) {
  const size_t i = ((size_t)blockIdx.x * 256 + threadIdx.x) * 8;
  const int4 a = *(const int4*)(Q + i);
  const int4 b = *(const int4*)(Q + i + 4);
  union { float f; u32 u; } c;
  uint4 r;
  u32 t;
  c.f = (float)a.x; t = c.u >> 16; c.f = (float)a.y; r.x = t | (c.u & 0xffff0000u);
  c.f = (float)a.z; t = c.u >> 16; c.f = (float)a.w; r.y = t | (c.u & 0xffff0000u);
  c.f = (float)b.x; t = c.u >> 16; c.f = (float)b.y; r.z = t | (c.u & 0xffff0000u);
  c.f = (float)b.z; t = c.u >> 16; c.f = (float)b.w; r.w = t | (c.u & 0xffff0000u);
  *(uint4*)(W + i) = r;
}

// ---------- concat 3x2048 f32 scales ----------
__global__ __launch_bounds__(256) void scat_k(const float* __restrict__ a,
    const float* __restrict__ b, const float* __restrict__ c, float* __restrict__ o) {
  const int i = blockIdx.x * 256 + threadIdx.x;   // 24*256 = 6144
  o[i] = (i < 2048) ? a[i] : (i < 4096 ? b[i - 2048] : c[i - 4096]);
}

// ---------- LayerNorm + FWHT(2048), one row per block; out bf16 ----------
template<typename T>
__global__ __launch_bounds__(256) void ln_fwht_k(const T* __restrict__ X,
    const float* __restrict__ G, const float* __restrict__ Bt, u16* __restrict__ O) {
  __shared__ float buf[2048];
  __shared__ float red[8];
  const int tid = threadIdx.x;
  const int lane = tid & 63, wave = tid >> 6;
  const size_t base = (size_t)blockIdx.x * 2048;
  float v[8]; load8(X + base + tid*8, v);
  float s = 0.f, s2 = 0.f;
  for (int j = 0; j < 8; ++j) { s += v[j]; s2 += v[j]*v[j]; }
  for (int m = 1; m < 64; m <<= 1) { s += __shfl_xor(s, m, 64); s2 += __shfl_xor(s2, m, 64); }
  if (lane == 0) { red[wave] = s; red[4 + wave] = s2; }
  __syncthreads();
  s  = red[0] + red[1] + red[2] + red[3];
  s2 = red[4] + red[5] + red[6] + red[7];
  const float mu = s * (1.f/2048.f);
  const float rstd = rsqrtf(s2 * (1.f/2048.f) - mu*mu + 1e-5f);
  float g[8], bb[8];
  load8(G + tid*8, g); load8(Bt + tid*8, bb);
  for (int j = 0; j < 8; ++j) buf[tid*8 + j] = (v[j] - mu) * rstd * g[j] + bb[j];
  __syncthreads();
  for (int h = 1; h < 2048; h <<= 1) {
    for (int p = 0; p < 4; ++p) {
      const int idx = p*256 + tid;
      const int i = ((idx & ~(h-1)) << 1) | (idx & (h-1));
      const float a = buf[i], c = buf[i + h];
      buf[i] = a + c; buf[i + h] = a - c;
    }
    __syncthreads();
  }
  float o[8];
  for (int j = 0; j < 8; ++j) o[j] = buf[tid*8 + j] * 0.02209708691207961f; // 1/sqrt(2048)
  *(uint4*)&O[base + tid*8] = pack8(o);
}

// ---------- in-place FWHT<N> on bf16 rows ----------
template<int N>
__global__ __launch_bounds__(256) void fwht_ip(u16* __restrict__ D) {
  __shared__ float buf[N];
  const int tid = threadIdx.x;
  const size_t base = (size_t)blockIdx.x * N;
  constexpr int V8 = N / (8*256);
  for (int i = 0; i < V8; ++i) {
    uint4 raw = *(const uint4*)&D[base + (i*256 + tid)*8];
    float v[8]; unpack8(raw, v);
    for (int j = 0; j < 8; ++j) buf[(i*256 + tid)*8 + j] = v[j];
  }
  __syncthreads();
  constexpr int PAIRS = N / 2 / 256;
  for (int h = 1; h < N; h <<= 1) {
    for (int p = 0; p < PAIRS; ++p) {
      const int idx = p*256 + tid;
      const int i = ((idx & ~(h-1)) << 1) | (idx & (h-1));
      const float a = buf[i], c = buf[i + h];
      buf[i] = a + c; buf[i + h] = a - c;
    }
    __syncthreads();
  }
  const float sc = rsqrtf((float)N);
  for (int i = 0; i < V8; ++i) {
    float v[8];
    for (int j = 0; j < 8; ++j) v[j] = buf[(i*256 + tid)*8 + j] * sc;
    *(uint4*)&D[base + (i*256 + tid)*8] = pack8(v);
  }
}

// ---------- 256x128 triple-buffered GEMM, 2 MFMA-phases per K-tile ----------
// C[m][n] = (sum_k A[m][k] * Bw[n][k]) * S[n]  (+bias, gelu, +res)
// BM=256 BN=128 BK=64, 512 thr = 8 waves (4M x 2N), per-wave C 64x64.
// Per K-tile: 2 phases; each = {8 ds_read + 3 gload-issue -> s_barrier ->
// [compiler lgkm waits] setprio(1) 16xMFMA setprio(0) -> s_barrier}.
// vmcnt(6) once per tile (mid-P1): tile t+1's 6 loads confirmed, tile t+2's
// 6 stay in flight across the barrier (T3+T4). 3 LDS bufs, 2-tile lookahead.
// LDS read swizzle (rule 21 both-sides): slot = chunk ^ (row&7); staged via
// pre-swizzled per-lane GLOBAL source col, linear gload_lds dest.
__global__ __launch_bounds__(512, 1) void gemm256(
    const u16* __restrict__ A, const u16* __restrict__ Bw, const float* __restrict__ S,
    void* __restrict__ C, int ldc, int M, int N, int K,
    const float* __restrict__ bias, const float* __restrict__ resf,
    const u16* __restrict__ resb, int dogelu, int outf32)
{
  __shared__ alignas(16) u16 sA[3][256*64];
  __shared__ alignas(16) u16 sB[3][128*64];
  const int tid = threadIdx.x;
  const int lane = tid & 63, wave = tid >> 6;       // 8 waves
  const int quad = lane >> 4, l16 = lane & 15;
  const int wm = wave & 3, wn = wave >> 2;          // 4 M-waves x 2 N-waves
  const int nwg = gridDim.x * gridDim.y;
  int flat = blockIdx.y * gridDim.x + blockIdx.x;
  if ((nwg & 7) == 0) flat = (flat & 7) * (nwg >> 3) + (flat >> 3);
  const long tM = (long)(flat % gridDim.x) * 256;
  const long tN = (long)(flat / gridDim.x) * 128;

  // staging: chunk = 1024B = 8 rows x 128B; lane -> row rc, 16B slot lane&7,
  // global source col chunk pre-swizzled by ^rc.
  const int rc = lane >> 3;
  const int cswz = ((lane & 7) ^ rc) * 8;
  const u16* Ab = A  + (size_t)(tM + rc) * K + cswz;
  const u16* Bb = Bw + (size_t)(tN + rc) * K + cswz;

  f32x4 acc[4][4] = {};
  const int ntk = K >> 6;

  auto stageA = [&](int buf, int k0, int i) {
    const int chunk = i*8 + wave;
    gload16(Ab + (size_t)(chunk*8)*K + k0, &sA[buf][chunk*512]);
  };
  auto stageB = [&](int buf, int k0, int i) {
    const int chunk = i*8 + wave;
    gload16(Bb + (size_t)(chunk*8)*K + k0, &sB[buf][chunk*512]);
  };

  // prologue: tiles 0 and 1 fully staged (6 loads each)
  stageA(0, 0, 0); stageA(0, 0, 1); stageA(0, 0, 2); stageA(0, 0, 3);
  stageB(0, 0, 0); stageB(0, 0, 1);
  if (ntk > 1) {
    stageA(1, 64, 0); stageA(1, 64, 1); stageA(1, 64, 2); stageA(1, 64, 3);
    stageB(1, 64, 0); stageB(1, 64, 1);
  }
  asm volatile("s_waitcnt vmcnt(6)" ::: "memory");   // tile 0 complete
  __builtin_amdgcn_s_barrier();
  __builtin_amdgcn_sched_barrier(0);

  for (int t = 0; t < ntk; ++t) {
    const int buf = t % 3, nb = (t + 2) % 3;
    const bool more = (t + 2) < ntk;
    const int k2 = (t + 2) << 6;
    bf16x8 af[4], bq[4];
#pragma unroll
    for (int ks = 0; ks < 2; ++ks) {
      const int oc = ks*4 + quad;
#pragma unroll
      for (int mt = 0; mt < 4; ++mt)
        af[mt] = *(const bf16x8*)&sA[buf][(wm*64 + mt*16 + l16)*64 + (oc ^ (l16 & 7))*8];
#pragma unroll
      for (int nt = 0; nt < 4; ++nt)
        bq[nt] = *(const bf16x8*)&sB[buf][(wn*64 + nt*16 + l16)*64 + (oc ^ (l16 & 7))*8];
      if (more) {
        if (ks == 0) { stageA(nb, k2, 0); stageA(nb, k2, 1); stageB(nb, k2, 0); }
        else         { stageA(nb, k2, 2); stageA(nb, k2, 3); stageB(nb, k2, 1); }
      }
      if (ks == 1 && t + 1 < ntk) {
        if (more) asm volatile("s_waitcnt vmcnt(6)" ::: "memory");
        else      asm volatile("s_waitcnt vmcnt(0)" ::: "memory");
      }
      __builtin_amdgcn_s_barrier();
      __builtin_amdgcn_sched_barrier(0);
      __builtin_amdgcn_s_setprio(1);
#pragma unroll
      for (int mt = 0; mt < 4; ++mt)
#pragma unroll
        for (int nt = 0; nt < 4; ++nt)
          acc[mt][nt] = __builtin_amdgcn_mfma_f32_16x16x32_bf16(af[mt], bq[nt], acc[mt][nt], 0, 0, 0);
      __builtin_amdgcn_s_setprio(0);
      __builtin_amdgcn_s_barrier();
      __builtin_amdgcn_sched_barrier(0);
    }
  }

#pragma unroll
  for (int in = 0; in < 4; ++in) {
    const long col = tN + wn*64 + in*16 + l16;
    const float sc = S[col];
    const float bv = bias ? bias[col] : 0.f;
#pragma unroll
    for (int im = 0; im < 4; ++im) {
      const long row0 = tM + wm*64 + im*16 + quad*4;
#pragma unroll
      for (int r = 0; r < 4; ++r) {
        float v = acc[im][in][r] * sc + bv;
        if (dogelu) v = 0.5f * v * (1.f + erff(v * 0.7071067811865475f));
        const size_t off = (size_t)(row0 + r)*ldc + col;
        if (resf) v += resf[off];
        if (resb) v += bf2f(resb[off]);
        if (outf32) ((float*)C)[off] = v;
        else        ((u16*)C)[off]   = f2bf(v);
      }
    }
  }
}

// ---------- fused MFMA attention: QKV packed [4096, 6144] bf16, O [4096, 2048] bf16 ----------
// All LDS tiles (Q, K, P, V^T) use the swz8 chunk swizzle (both sides).
// V: pair-rows loaded early to regs (T14), written as packed b32 (2-way, free).
__global__ __launch_bounds__(256, 2) void attn_k(const u16* __restrict__ QKV, u16* __restrict__ O)
{
  __shared__ alignas(16) u16 sKV[16384];  // K tile [128][128], then V^T tile [d=128][kv=128]
  __shared__ alignas(16) u16 sP[16384];   // Q tile [128][128] at start, then per-wave P [32][128]
  const int tid = threadIdx.x;
  const int lane = tid & 63, wave = tid >> 6;
  const int quad = lane >> 4, l16 = lane & 15;
  const int qt = blockIdx.x;        // 0..7
  const int bh = blockIdx.y;        // 0..63
  const int b = bh >> 4, h = bh & 15;
  const size_t rb = (size_t)b * 1024;
  const u16* Qg = QKV + (rb + (size_t)qt*128)*6144 + h*128;
  const u16* Kg = QKV + rb*6144 + 2048 + h*128;
  const u16* Vg = QKV + rb*6144 + 4096 + h*128;

  for (int c = 0; c < 8; ++c) {
    const int chunk = c*4 + wave;        // 0..31, 1 KiB = 4 rows
    const int r = chunk*4 + quad;
    gload16(Qg + (size_t)r*6144 + (l16 ^ swz8(r))*8, &sP[chunk*512]);
  }
  __syncthreads();
  bf16x8 aq[2][4];
  for (int im = 0; im < 2; ++im)
    for (int kk = 0; kk < 4; ++kk) {
      const int row = wave*32 + im*16 + l16;
      aq[im][kk] = *(const bf16x8*)&sP[row*128 + ((kk*4 + quad) ^ swz8(row))*8];
    }

  float mrun[2][4], lrun[2][4];
  f32x4 oacc[2][8] = {};
  for (int im = 0; im < 2; ++im)
    for (int r = 0; r < 4; ++r) { mrun[im][r] = -1e30f; lrun[im][r] = 0.f; }

  for (int kt = 0; kt < 8; ++kt) {
    __syncthreads();
    for (int c = 0; c < 8; ++c) {
      const int chunk = c*4 + wave;
      const int r = chunk*4 + quad;
      gload16(Kg + (size_t)(kt*128 + r)*6144 + (l16 ^ swz8(r))*8, &sKV[chunk*512]);
    }
    // early V loads (T14): latency hidden under QK^T + softmax
    uint4 va[4], vb[4];
#pragma unroll
    for (int c = 0; c < 4; ++c) {
      const int task = c*256 + tid;
      const int kv = (task >> 4) * 2;
      const int d0 = (task & 15) * 8;
      va[c] = *(const uint4*)(Vg + (size_t)(kt*128 + kv    )*6144 + d0);
      vb[c] = *(const uint4*)(Vg + (size_t)(kt*128 + kv + 1)*6144 + d0);
    }
    __syncthreads();
    f32x4 sf[2][8] = {};
#pragma unroll
    for (int kk = 0; kk < 4; ++kk)
#pragma unroll
      for (int jn = 0; jn < 8; ++jn) {
        const int rk = jn*16 + l16;
        const bf16x8 bk = *(const bf16x8*)&sKV[rk*128 + ((kk*4 + quad) ^ swz8(rk))*8];
        sf[0][jn] = __builtin_amdgcn_mfma_f32_16x16x32_bf16(aq[0][kk], bk, sf[0][jn], 0, 0, 0);
        sf[1][jn] = __builtin_amdgcn_mfma_f32_16x16x32_bf16(aq[1][kk], bk, sf[1][jn], 0, 0, 0);
      }
    const float scale = 0.08838834764831845f;   // 1/sqrt(128)
#pragma unroll
    for (int im = 0; im < 2; ++im)
#pragma unroll
      for (int r = 0; r < 4; ++r) {
        float mx = -1e30f;
        for (int jn = 0; jn < 8; ++jn) mx = fmaxf(mx, sf[im][jn][r] * scale);
        for (int m = 1; m < 16; m <<= 1) mx = fmaxf(mx, __shfl_xor(mx, m, 64));
        const float mold = mrun[im][r];
        const float mnew = fmaxf(mold, mx);
        const float alpha = __expf(mold - mnew);
        float ls = 0.f;
        const int rl = im*16 + quad*4 + r;
        for (int jn = 0; jn < 8; ++jn) {
          const float p = __expf(sf[im][jn][r] * scale - mnew);
          ls += p;
          sP[wave*4096 + rl*128 + (((jn*2 + (l16 >> 3)) ^ swz8(rl))*8 | (l16 & 7))] = f2bf(p);
        }
        for (int m = 1; m < 16; m <<= 1) ls += __shfl_xor(ls, m, 64);
        lrun[im][r] = lrun[im][r]*alpha + ls;
        mrun[im][r] = mnew;
        for (int od = 0; od < 8; ++od) oacc[im][od][r] *= alpha;
      }
    __syncthreads();
    // V^T tile from regs: packed b32 writes, swizzled chunk (2-way, free)
#pragma unroll
    for (int c = 0; c < 4; ++c) {
      const int task = c*256 + tid;
      const int kv = (task >> 4) * 2;
      const int d0 = (task & 15) * 8;
      const int cc = kv >> 3;
      const u16* pa = (const u16*)&va[c];
      const u16* pb = (const u16*)&vb[c];
#pragma unroll
      for (int j = 0; j < 8; ++j) {
        const int row = d0 + j;
        const int col = ((cc ^ swz8(row))*8) | (kv & 7);
        *(u32*)&sKV[row*128 + col] = (u32)pa[j] | ((u32)pb[j] << 16);
      }
    }
    __syncthreads();
#pragma unroll
    for (int kk = 0; kk < 4; ++kk) {
      const int r0 = l16, r1 = 16 + l16;
      const bf16x8 ap0 = *(const bf16x8*)&sP[wave*4096 + r0*128 + ((kk*4 + quad) ^ swz8(r0))*8];
      const bf16x8 ap1 = *(const bf16x8*)&sP[wave*4096 + r1*128 + ((kk*4 + quad) ^ swz8(r1))*8];
#pragma unroll
      for (int od = 0; od < 8; ++od) {
        const int rv = od*16 + l16;
        const bf16x8 bv = *(const bf16x8*)&sKV[rv*128 + ((kk*4 + quad) ^ swz8(rv))*8];
        oacc[0][od] = __builtin_amdgcn_mfma_f32_16x16x32_bf16(ap0, bv, oacc[0][od], 0, 0, 0);
        oacc[1][od] = __builtin_amdgcn_mfma_f32_16x16x32_bf16(ap1, bv, oacc[1][od], 0, 0, 0);
      }
    }
  }
  for (int im = 0; im < 2; ++im)
    for (int r = 0; r < 4; ++r) {
      const float inv = 1.f / lrun[im][r];
      const size_t row = rb + (size_t)qt*128 + wave*32 + im*16 + quad*4 + r;
      for (int od = 0; od < 8; ++od)
        O[row*2048 + h*128 + od*16 + l16] = f2bf(oacc[im][od][r] * inv);
    }
}

extern "C" void kernel_launch(void* const* d_in, const int* in_sizes, int n_in,
                              void* d_out, int out_size, void* d_ws, size_t ws_size,
                              hipStream_t stream) {
  const float* x    = (const float*)d_in[0];
  const float* ln1g = (const float*)d_in[1];
  const float* ln1b = (const float*)d_in[2];
  const float* ln2g = (const float*)d_in[3];
  const float* ln2b = (const float*)d_in[4];
  const int* Qq  = (const int*)d_in[5];  const float* sq  = (const float*)d_in[6];
  const int* Qk  = (const int*)d_in[7];  const float* sk  = (const float*)d_in[8];
  const int* Qv  = (const int*)d_in[9];  const float* sv  = (const float*)d_in[10];
  const int* Qo  = (const int*)d_in[11]; const float* so  = (const float*)d_in[12];
  const int* Qf1 = (const int*)d_in[13]; const float* sf1 = (const float*)d_in[14];
  const float* bf1 = (const float*)d_in[15];
  const int* Qf2 = (const int*)d_in[16]; const float* sf2 = (const float*)d_in[17];
  const float* bf2 = (const float*)d_in[18];

  // arena (u16 elems), 96 MiB, byte map:
  //   XH   [ 0,16) MiB : XH1 -> ATT -> XH2
  //   Wq   [16,40) MiB : QKV weights concat [6144,2048] bf16 (24 MiB)
  //   Wsl  [16,32) MiB : rotating weight slot (Qo 8 MiB, FF1 halves 16 MiB)
  //   QKV  [40,88) MiB : [4096,6144] bf16
  //   FF   [32,96) MiB : [4096,8192] bf16 (after attn; QKV dead)
  //   Wf2  [ 0,32) MiB : FF2 weight [2048,8192] bf16 (XH & Wsl dead by then)
  //   Scat [88, +24KiB): concat scales f32[6144]
  u16* XH   = (u16*)d_ws;
  u16* Wq   = XH + 8388608;
  u16* Wsl  = XH + 8388608;
  u16* QKVb = XH + 20971520;
  u16* FFb  = XH + 16777216;
  u16* Wf2  = XH;
  float* Scat = (float*)(XH + 46137344);
  float* Xout = (float*)d_out;
  if (ws_size < (size_t)100663296) return;   // guard (signals via poisoned d_out)

  // 1) LN1 + FWHT (f32 x -> bf16 XH1)
  ln_fwht_k<float><<<4096, 256, 0, stream>>>(x, ln1g, ln1b, XH);

  // 2) fused QKV projection: one N=6144 GEMM (concat weights + scales)
  cvt_k<<<2048, 256, 0, stream>>>(Qq, Wq);
  cvt_k<<<2048, 256, 0, stream>>>(Qk, Wq + 4194304);
  cvt_k<<<2048, 256, 0, stream>>>(Qv, Wq + 8388608);
  scat_k<<<24, 256, 0, stream>>>(sq, sk, sv, Scat);
  gemm256<<<dim3(16,48), 512, 0, stream>>>(XH, Wq, Scat, QKVb, 6144, 4096, 6144, 2048,
                                           nullptr, nullptr, nullptr, 0, 0);

  // 3) attention -> ATT (XH region)
  attn_k<<<dim3(8, 64), 256, 0, stream>>>(QKVb, XH);

  // 4) FWHT(2048) in-place on ATT
  fwht_ip<2048><<<4096, 256, 0, stream>>>(XH);

  // 5) O-proj + residual(x, f32) -> X1 = d_out (f32)
  cvt_k<<<2048, 256, 0, stream>>>(Qo, Wsl);
  gemm256<<<dim3(16,16), 512, 0, stream>>>(XH, Wsl, so, Xout, 2048, 4096, 2048, 2048,
                                           nullptr, x, nullptr, 0, 1);

  // 6) LN2 + FWHT: X1 (f32, in d_out) -> XH2
  ln_fwht_k<float><<<4096, 256, 0, stream>>>(Xout, ln2g, ln2b, XH);

  // 7) FF1 + bias + exact GELU -> FF (bf16), split along N (weight half fits Wsl)
  cvt_k<<<4096, 256, 0, stream>>>(Qf1, Wsl);
  gemm256<<<dim3(16,32), 512, 0, stream>>>(XH, Wsl, sf1,        FFb + 0,    8192, 4096, 4096, 2048,
                                           bf1,        nullptr, nullptr, 1, 0);
  cvt_k<<<4096, 256, 0, stream>>>(Qf1 + (size_t)4096*2048, Wsl);
  gemm256<<<dim3(16,32), 512, 0, stream>>>(XH, Wsl, sf1 + 4096, FFb + 4096, 8192, 4096, 4096, 2048,
                                           bf1 + 4096, nullptr, nullptr, 1, 0);

  // 8) FWHT(8192) in-place on FF
  fwht_ip<8192><<<4096, 256, 0, stream>>>(FFb);

  // 9) FF2 (unsplit, K=8192) + bias + residual(X1 in d_out) -> d_out (f32)
  cvt_k<<<8192, 256, 0, stream>>>(Qf2, Wf2);
  gemm256<<<dim3(16,16), 512, 0, stream>>>(FFb, Wf2, sf2, Xout, 2048, 4096, 2048, 8192,
                                           bf2, Xout, nullptr, 0, 1);
}

// Round 5
// 1232.852 us; speedup vs baseline: 1.0502x; 1.0502x over previous
//
#include <hip/hip_runtime.h>
#include <cstdint>
#include <cstddef>

typedef unsigned short u16;
typedef unsigned int   u32;
typedef __bf16 bf16x8 __attribute__((ext_vector_type(8)));
typedef float  f32x4  __attribute__((ext_vector_type(4)));

// ---------- bf16 helpers (RNE) ----------
__device__ __forceinline__ float bf2f(u16 u) {
  union { u32 i; float f; } v; v.i = ((u32)u) << 16; return v.f;
}
__device__ __forceinline__ u16 f2bf(float f) {
  union { float f; u32 i; } v; v.f = f;
  u32 r = v.i + 0x7fffu + ((v.i >> 16) & 1u);
  return (u16)(r >> 16);
}
__device__ __forceinline__ void unpack8(uint4 raw, float* v) {
  v[0]=bf2f(raw.x&0xffff); v[1]=bf2f(raw.x>>16);
  v[2]=bf2f(raw.y&0xffff); v[3]=bf2f(raw.y>>16);
  v[4]=bf2f(raw.z&0xffff); v[5]=bf2f(raw.z>>16);
  v[6]=bf2f(raw.w&0xffff); v[7]=bf2f(raw.w>>16);
}
__device__ __forceinline__ uint4 pack8(const float* v) {
  uint4 r;
  r.x = (u32)f2bf(v[0]) | ((u32)f2bf(v[1])<<16);
  r.y = (u32)f2bf(v[2]) | ((u32)f2bf(v[3])<<16);
  r.z = (u32)f2bf(v[4]) | ((u32)f2bf(v[5])<<16);
  r.w = (u32)f2bf(v[6]) | ((u32)f2bf(v[7])<<16);
  return r;
}
__device__ __forceinline__ void gload16(const void* g, void* l) {
  __builtin_amdgcn_global_load_lds((const __attribute__((address_space(1))) void*)g,
                                   (__attribute__((address_space(3))) void*)l, 16, 0, 0);
}
// attn LDS chunk swizzle: row-dependent XOR on the 16B-chunk index.
// Free on b128 reads (quarter-wave: 2 lanes/slot) AND on b32 V-writes.
__device__ __forceinline__ int swz8(int row) { return ((row >> 3) ^ row) & 7; }

// ---------- load 8 consecutive elems as f32, from f32 or bf16 source ----------
template<typename T>
__device__ __forceinline__ void load8(const T* p, float* v);
template<> __device__ __forceinline__ void load8<float>(const float* p, float* v) {
  const float4 a = ((const float4*)p)[0];
  const float4 b = ((const float4*)p)[1];
  v[0]=a.x; v[1]=a.y; v[2]=a.z; v[3]=a.w;
  v[4]=b.x; v[5]=b.y; v[6]=b.z; v[7]=b.w;
}
template<> __device__ __forceinline__ void load8<u16>(const u16* p, float* v) {
  unpack8(*(const uint4*)p, v);
}

// ---------- int32 (|q|<=127) -> bf16, EXACT (high-16 truncation of f32) ----------
__global__ __launch_bounds__(256) void cvt_k(const int* __restrict__ Q, u16* __restrict__ W) {
  const size_t i = ((size_t)blockIdx.x * 256 + threadIdx.x) * 8;
  const int4 a = *(const int4*)(Q + i);
  const int4 b = *(const int4*)(Q + i + 4);
  union { float f; u32 u; } c;
  uint4 r;
  u32 t;
  c.f = (float)a.x; t = c.u >> 16; c.f = (float)a.y; r.x = t | (c.u & 0xffff0000u);
  c.f = (float)a.z; t = c.u >> 16; c.f = (float)a.w; r.y = t | (c.u & 0xffff0000u);
  c.f = (float)b.x; t = c.u >> 16; c.f = (float)b.y; r.z = t | (c.u & 0xffff0000u);
  c.f = (float)b.z; t = c.u >> 16; c.f = (float)b.w; r.w = t | (c.u & 0xffff0000u);
  *(uint4*)(W + i) = r;
}

// ---------- concat 3x2048 f32 scales ----------
__global__ __launch_bounds__(256) void scat_k(const float* __restrict__ a,
    const float* __restrict__ b, const float* __restrict__ c, float* __restrict__ o) {
  const int i = blockIdx.x * 256 + threadIdx.x;   // 24*256 = 6144
  o[i] = (i < 2048) ? a[i] : (i < 4096 ? b[i - 2048] : c[i - 4096]);
}

// ---------- LayerNorm + FWHT(2048), one row per block; out bf16 ----------
template<typename T>
__global__ __launch_bounds__(256) void ln_fwht_k(const T* __restrict__ X,
    const float* __restrict__ G, const float* __restrict__ Bt, u16* __restrict__ O) {
  __shared__ float buf[2048];
  __shared__ float red[8];
  const int tid = threadIdx.x;
  const int lane = tid & 63, wave = tid >> 6;
  const size_t base = (size_t)blockIdx.x * 2048;
  float v[8]; load8(X + base + tid*8, v);
  float s = 0.f, s2 = 0.f;
  for (int j = 0; j < 8; ++j) { s += v[j]; s2 += v[j]*v[j]; }
  for (int m = 1; m < 64; m <<= 1) { s += __shfl_xor(s, m, 64); s2 += __shfl_xor(s2, m, 64); }
  if (lane == 0) { red[wave] = s; red[4 + wave] = s2; }
  __syncthreads();
  s  = red[0] + red[1] + red[2] + red[3];
  s2 = red[4] + red[5] + red[6] + red[7];
  const float mu = s * (1.f/2048.f);
  const float rstd = rsqrtf(s2 * (1.f/2048.f) - mu*mu + 1e-5f);
  float g[8], bb[8];
  load8(G + tid*8, g); load8(Bt + tid*8, bb);
  for (int j = 0; j < 8; ++j) buf[tid*8 + j] = (v[j] - mu) * rstd * g[j] + bb[j];
  __syncthreads();
  for (int h = 1; h < 2048; h <<= 1) {
    for (int p = 0; p < 4; ++p) {
      const int idx = p*256 + tid;
      const int i = ((idx & ~(h-1)) << 1) | (idx & (h-1));
      const float a = buf[i], c = buf[i + h];
      buf[i] = a + c; buf[i + h] = a - c;
    }
    __syncthreads();
  }
  float o[8];
  for (int j = 0; j < 8; ++j) o[j] = buf[tid*8 + j] * 0.02209708691207961f; // 1/sqrt(2048)
  *(uint4*)&O[base + tid*8] = pack8(o);
}

// ---------- in-place FWHT<N> on bf16 rows ----------
template<int N>
__global__ __launch_bounds__(256) void fwht_ip(u16* __restrict__ D) {
  __shared__ float buf[N];
  const int tid = threadIdx.x;
  const size_t base = (size_t)blockIdx.x * N;
  constexpr int V8 = N / (8*256);
  for (int i = 0; i < V8; ++i) {
    uint4 raw = *(const uint4*)&D[base + (i*256 + tid)*8];
    float v[8]; unpack8(raw, v);
    for (int j = 0; j < 8; ++j) buf[(i*256 + tid)*8 + j] = v[j];
  }
  __syncthreads();
  constexpr int PAIRS = N / 2 / 256;
  for (int h = 1; h < N; h <<= 1) {
    for (int p = 0; p < PAIRS; ++p) {
      const int idx = p*256 + tid;
      const int i = ((idx & ~(h-1)) << 1) | (idx & (h-1));
      const float a = buf[i], c = buf[i + h];
      buf[i] = a + c; buf[i + h] = a - c;
    }
    __syncthreads();
  }
  const float sc = rsqrtf((float)N);
  for (int i = 0; i < V8; ++i) {
    float v[8];
    for (int j = 0; j < 8; ++j) v[j] = buf[(i*256 + tid)*8 + j] * sc;
    *(uint4*)&D[base + (i*256 + tid)*8] = pack8(v);
  }
}

// ---------- 256x128 triple-buffered GEMM, 2 MFMA-phases per K-tile ----------
// (unchanged from round 4 -- it improved; see journal)
__global__ __launch_bounds__(512, 1) void gemm256(
    const u16* __restrict__ A, const u16* __restrict__ Bw, const float* __restrict__ S,
    void* __restrict__ C, int ldc, int M, int N, int K,
    const float* __restrict__ bias, const float* __restrict__ resf,
    const u16* __restrict__ resb, int dogelu, int outf32)
{
  __shared__ alignas(16) u16 sA[3][256*64];
  __shared__ alignas(16) u16 sB[3][128*64];
  const int tid = threadIdx.x;
  const int lane = tid & 63, wave = tid >> 6;       // 8 waves
  const int quad = lane >> 4, l16 = lane & 15;
  const int wm = wave & 3, wn = wave >> 2;          // 4 M-waves x 2 N-waves
  const int nwg = gridDim.x * gridDim.y;
  int flat = blockIdx.y * gridDim.x + blockIdx.x;
  if ((nwg & 7) == 0) flat = (flat & 7) * (nwg >> 3) + (flat >> 3);
  const long tM = (long)(flat % gridDim.x) * 256;
  const long tN = (long)(flat / gridDim.x) * 128;

  const int rc = lane >> 3;
  const int cswz = ((lane & 7) ^ rc) * 8;
  const u16* Ab = A  + (size_t)(tM + rc) * K + cswz;
  const u16* Bb = Bw + (size_t)(tN + rc) * K + cswz;

  f32x4 acc[4][4] = {};
  const int ntk = K >> 6;

  auto stageA = [&](int buf, int k0, int i) {
    const int chunk = i*8 + wave;
    gload16(Ab + (size_t)(chunk*8)*K + k0, &sA[buf][chunk*512]);
  };
  auto stageB = [&](int buf, int k0, int i) {
    const int chunk = i*8 + wave;
    gload16(Bb + (size_t)(chunk*8)*K + k0, &sB[buf][chunk*512]);
  };

  stageA(0, 0, 0); stageA(0, 0, 1); stageA(0, 0, 2); stageA(0, 0, 3);
  stageB(0, 0, 0); stageB(0, 0, 1);
  if (ntk > 1) {
    stageA(1, 64, 0); stageA(1, 64, 1); stageA(1, 64, 2); stageA(1, 64, 3);
    stageB(1, 64, 0); stageB(1, 64, 1);
  }
  asm volatile("s_waitcnt vmcnt(6)" ::: "memory");   // tile 0 complete
  __builtin_amdgcn_s_barrier();
  __builtin_amdgcn_sched_barrier(0);

  for (int t = 0; t < ntk; ++t) {
    const int buf = t % 3, nb = (t + 2) % 3;
    const bool more = (t + 2) < ntk;
    const int k2 = (t + 2) << 6;
    bf16x8 af[4], bq[4];
#pragma unroll
    for (int ks = 0; ks < 2; ++ks) {
      const int oc = ks*4 + quad;
#pragma unroll
      for (int mt = 0; mt < 4; ++mt)
        af[mt] = *(const bf16x8*)&sA[buf][(wm*64 + mt*16 + l16)*64 + (oc ^ (l16 & 7))*8];
#pragma unroll
      for (int nt = 0; nt < 4; ++nt)
        bq[nt] = *(const bf16x8*)&sB[buf][(wn*64 + nt*16 + l16)*64 + (oc ^ (l16 & 7))*8];
      if (more) {
        if (ks == 0) { stageA(nb, k2, 0); stageA(nb, k2, 1); stageB(nb, k2, 0); }
        else         { stageA(nb, k2, 2); stageA(nb, k2, 3); stageB(nb, k2, 1); }
      }
      if (ks == 1 && t + 1 < ntk) {
        if (more) asm volatile("s_waitcnt vmcnt(6)" ::: "memory");
        else      asm volatile("s_waitcnt vmcnt(0)" ::: "memory");
      }
      __builtin_amdgcn_s_barrier();
      __builtin_amdgcn_sched_barrier(0);
      __builtin_amdgcn_s_setprio(1);
#pragma unroll
      for (int mt = 0; mt < 4; ++mt)
#pragma unroll
        for (int nt = 0; nt < 4; ++nt)
          acc[mt][nt] = __builtin_amdgcn_mfma_f32_16x16x32_bf16(af[mt], bq[nt], acc[mt][nt], 0, 0, 0);
      __builtin_amdgcn_s_setprio(0);
      __builtin_amdgcn_s_barrier();
      __builtin_amdgcn_sched_barrier(0);
    }
  }

#pragma unroll
  for (int in = 0; in < 4; ++in) {
    const long col = tN + wn*64 + in*16 + l16;
    const float sc = S[col];
    const float bv = bias ? bias[col] : 0.f;
#pragma unroll
    for (int im = 0; im < 4; ++im) {
      const long row0 = tM + wm*64 + im*16 + quad*4;
#pragma unroll
      for (int r = 0; r < 4; ++r) {
        float v = acc[im][in][r] * sc + bv;
        if (dogelu) v = 0.5f * v * (1.f + erff(v * 0.7071067811865475f));
        const size_t off = (size_t)(row0 + r)*ldc + col;
        if (resf) v += resf[off];
        if (resb) v += bf2f(resb[off]);
        if (outf32) ((float*)C)[off] = v;
        else        ((u16*)C)[off]   = f2bf(v);
      }
    }
  }
}

// ---------- fused MFMA attention: QKV packed [4096, 6144] bf16, O [4096, 2048] bf16 ----------
// All LDS tiles (Q, K, P, V^T) use the swz8 chunk swizzle (both sides).
// V: loaded AFTER softmax (short reg lifetime -- round-4's early-load spilled
// to scratch: WRITE_SIZE 27->100MB, FETCH 169->465MB), pair-rows written as
// packed b32 (2-way, free).
__global__ __launch_bounds__(256, 2) void attn_k(const u16* __restrict__ QKV, u16* __restrict__ O)
{
  __shared__ alignas(16) u16 sKV[16384];  // K tile [128][128], then V^T tile [d=128][kv=128]
  __shared__ alignas(16) u16 sP[16384];   // Q tile [128][128] at start, then per-wave P [32][128]
  const int tid = threadIdx.x;
  const int lane = tid & 63, wave = tid >> 6;
  const int quad = lane >> 4, l16 = lane & 15;
  const int qt = blockIdx.x;        // 0..7
  const int bh = blockIdx.y;        // 0..63
  const int b = bh >> 4, h = bh & 15;
  const size_t rb = (size_t)b * 1024;
  const u16* Qg = QKV + (rb + (size_t)qt*128)*6144 + h*128;
  const u16* Kg = QKV + rb*6144 + 2048 + h*128;
  const u16* Vg = QKV + rb*6144 + 4096 + h*128;

  for (int c = 0; c < 8; ++c) {
    const int chunk = c*4 + wave;        // 0..31, 1 KiB = 4 rows
    const int r = chunk*4 + quad;
    gload16(Qg + (size_t)r*6144 + (l16 ^ swz8(r))*8, &sP[chunk*512]);
  }
  __syncthreads();
  bf16x8 aq[2][4];
  for (int im = 0; im < 2; ++im)
    for (int kk = 0; kk < 4; ++kk) {
      const int row = wave*32 + im*16 + l16;
      aq[im][kk] = *(const bf16x8*)&sP[row*128 + ((kk*4 + quad) ^ swz8(row))*8];
    }

  float mrun[2][4], lrun[2][4];
  f32x4 oacc[2][8] = {};
  for (int im = 0; im < 2; ++im)
    for (int r = 0; r < 4; ++r) { mrun[im][r] = -1e30f; lrun[im][r] = 0.f; }

  for (int kt = 0; kt < 8; ++kt) {
    __syncthreads();
    for (int c = 0; c < 8; ++c) {
      const int chunk = c*4 + wave;
      const int r = chunk*4 + quad;
      gload16(Kg + (size_t)(kt*128 + r)*6144 + (l16 ^ swz8(r))*8, &sKV[chunk*512]);
    }
    __syncthreads();
    f32x4 sf[2][8] = {};
#pragma unroll
    for (int kk = 0; kk < 4; ++kk)
#pragma unroll
      for (int jn = 0; jn < 8; ++jn) {
        const int rk = jn*16 + l16;
        const bf16x8 bk = *(const bf16x8*)&sKV[rk*128 + ((kk*4 + quad) ^ swz8(rk))*8];
        sf[0][jn] = __builtin_amdgcn_mfma_f32_16x16x32_bf16(aq[0][kk], bk, sf[0][jn], 0, 0, 0);
        sf[1][jn] = __builtin_amdgcn_mfma_f32_16x16x32_bf16(aq[1][kk], bk, sf[1][jn], 0, 0, 0);
      }
    const float scale = 0.08838834764831845f;   // 1/sqrt(128)
#pragma unroll
    for (int im = 0; im < 2; ++im)
#pragma unroll
      for (int r = 0; r < 4; ++r) {
        float mx = -1e30f;
        for (int jn = 0; jn < 8; ++jn) mx = fmaxf(mx, sf[im][jn][r] * scale);
        for (int m = 1; m < 16; m <<= 1) mx = fmaxf(mx, __shfl_xor(mx, m, 64));
        const float mold = mrun[im][r];
        const float mnew = fmaxf(mold, mx);
        const float alpha = __expf(mold - mnew);
        float ls = 0.f;
        const int rl = im*16 + quad*4 + r;
        for (int jn = 0; jn < 8; ++jn) {
          const float p = __expf(sf[im][jn][r] * scale - mnew);
          ls += p;
          sP[wave*4096 + rl*128 + (((jn*2 + (l16 >> 3)) ^ swz8(rl))*8 | (l16 & 7))] = f2bf(p);
        }
        for (int m = 1; m < 16; m <<= 1) ls += __shfl_xor(ls, m, 64);
        lrun[im][r] = lrun[im][r]*alpha + ls;
        mrun[im][r] = mnew;
        for (int od = 0; od < 8; ++od) oacc[im][od][r] *= alpha;
      }
    __syncthreads();
    // V^T tile: pair-rows loaded here (short reg lifetime), packed b32 writes,
    // swizzled chunk (2-way, free)
#pragma unroll
    for (int c = 0; c < 4; ++c) {
      const int task = c*256 + tid;
      const int kv = (task >> 4) * 2;
      const int d0 = (task & 15) * 8;
      const uint4 ra = *(const uint4*)(Vg + (size_t)(kt*128 + kv    )*6144 + d0);
      const uint4 rc = *(const uint4*)(Vg + (size_t)(kt*128 + kv + 1)*6144 + d0);
      const int cc = kv >> 3;
      const u16* pa = (const u16*)&ra;
      const u16* pb = (const u16*)&rc;
#pragma unroll
      for (int j = 0; j < 8; ++j) {
        const int row = d0 + j;
        const int col = ((cc ^ swz8(row))*8) | (kv & 7);
        *(u32*)&sKV[row*128 + col] = (u32)pa[j] | ((u32)pb[j] << 16);
      }
    }
    __syncthreads();
#pragma unroll
    for (int kk = 0; kk < 4; ++kk) {
      const int r0 = l16, r1 = 16 + l16;
      const bf16x8 ap0 = *(const bf16x8*)&sP[wave*4096 + r0*128 + ((kk*4 + quad) ^ swz8(r0))*8];
      const bf16x8 ap1 = *(const bf16x8*)&sP[wave*4096 + r1*128 + ((kk*4 + quad) ^ swz8(r1))*8];
#pragma unroll
      for (int od = 0; od < 8; ++od) {
        const int rv = od*16 + l16;
        const bf16x8 bv = *(const bf16x8*)&sKV[rv*128 + ((kk*4 + quad) ^ swz8(rv))*8];
        oacc[0][od] = __builtin_amdgcn_mfma_f32_16x16x32_bf16(ap0, bv, oacc[0][od], 0, 0, 0);
        oacc[1][od] = __builtin_amdgcn_mfma_f32_16x16x32_bf16(ap1, bv, oacc[1][od], 0, 0, 0);
      }
    }
  }
  for (int im = 0; im < 2; ++im)
    for (int r = 0; r < 4; ++r) {
      const float inv = 1.f / lrun[im][r];
      const size_t row = rb + (size_t)qt*128 + wave*32 + im*16 + quad*4 + r;
      for (int od = 0; od < 8; ++od)
        O[row*2048 + h*128 + od*16 + l16] = f2bf(oacc[im][od][r] * inv);
    }
}

extern "C" void kernel_launch(void* const* d_in, const int* in_sizes, int n_in,
                              void* d_out, int out_size, void* d_ws, size_t ws_size,
                              hipStream_t stream) {
  const float* x    = (const float*)d_in[0];
  const float* ln1g = (const float*)d_in[1];
  const float* ln1b = (const float*)d_in[2];
  const float* ln2g = (const float*)d_in[3];
  const float* ln2b = (const float*)d_in[4];
  const int* Qq  = (const int*)d_in[5];  const float* sq  = (const float*)d_in[6];
  const int* Qk  = (const int*)d_in[7];  const float* sk  = (const float*)d_in[8];
  const int* Qv  = (const int*)d_in[9];  const float* sv  = (const float*)d_in[10];
  const int* Qo  = (const int*)d_in[11]; const float* so  = (const float*)d_in[12];
  const int* Qf1 = (const int*)d_in[13]; const float* sf1 = (const float*)d_in[14];
  const float* bf1 = (const float*)d_in[15];
  const int* Qf2 = (const int*)d_in[16]; const float* sf2 = (const float*)d_in[17];
  const float* bf2 = (const float*)d_in[18];

  // arena (u16 elems), 96 MiB, byte map:
  //   XH   [ 0,16) MiB : XH1 -> ATT -> XH2
  //   Wq   [16,40) MiB : QKV weights concat [6144,2048] bf16 (24 MiB)
  //   Wsl  [16,32) MiB : rotating weight slot (Qo 8 MiB, FF1 halves 16 MiB)
  //   QKV  [40,88) MiB : [4096,6144] bf16
  //   FF   [32,96) MiB : [4096,8192] bf16 (after attn; QKV dead)
  //   Wf2  [ 0,32) MiB : FF2 weight [2048,8192] bf16 (XH & Wsl dead by then)
  //   Scat [88, +24KiB): concat scales f32[6144]
  u16* XH   = (u16*)d_ws;
  u16* Wq   = XH + 8388608;
  u16* Wsl  = XH + 8388608;
  u16* QKVb = XH + 20971520;
  u16* FFb  = XH + 16777216;
  u16* Wf2  = XH;
  float* Scat = (float*)(XH + 46137344);
  float* Xout = (float*)d_out;
  if (ws_size < (size_t)100663296) return;   // guard (signals via poisoned d_out)

  // 1) LN1 + FWHT (f32 x -> bf16 XH1)
  ln_fwht_k<float><<<4096, 256, 0, stream>>>(x, ln1g, ln1b, XH);

  // 2) fused QKV projection: one N=6144 GEMM (concat weights + scales)
  cvt_k<<<2048, 256, 0, stream>>>(Qq, Wq);
  cvt_k<<<2048, 256, 0, stream>>>(Qk, Wq + 4194304);
  cvt_k<<<2048, 256, 0, stream>>>(Qv, Wq + 8388608);
  scat_k<<<24, 256, 0, stream>>>(sq, sk, sv, Scat);
  gemm256<<<dim3(16,48), 512, 0, stream>>>(XH, Wq, Scat, QKVb, 6144, 4096, 6144, 2048,
                                           nullptr, nullptr, nullptr, 0, 0);

  // 3) attention -> ATT (XH region)
  attn_k<<<dim3(8, 64), 256, 0, stream>>>(QKVb, XH);

  // 4) FWHT(2048) in-place on ATT
  fwht_ip<2048><<<4096, 256, 0, stream>>>(XH);

  // 5) O-proj + residual(x, f32) -> X1 = d_out (f32)
  cvt_k<<<2048, 256, 0, stream>>>(Qo, Wsl);
  gemm256<<<dim3(16,16), 512, 0, stream>>>(XH, Wsl, so, Xout, 2048, 4096, 2048, 2048,
                                           nullptr, x, nullptr, 0, 1);

  // 6) LN2 + FWHT: X1 (f32, in d_out) -> XH2
  ln_fwht_k<float><<<4096, 256, 0, stream>>>(Xout, ln2g, ln2b, XH);

  // 7) FF1 + bias + exact GELU -> FF (bf16), split along N (weight half fits Wsl)
  cvt_k<<<4096, 256, 0, stream>>>(Qf1, Wsl);
  gemm256<<<dim3(16,32), 512, 0, stream>>>(XH, Wsl, sf1,        FFb + 0,    8192, 4096, 4096, 2048,
                                           bf1,        nullptr, nullptr, 1, 0);
  cvt_k<<<4096, 256, 0, stream>>>(Qf1 + (size_t)4096*2048, Wsl);
  gemm256<<<dim3(16,32), 512, 0, stream>>>(XH, Wsl, sf1 + 4096, FFb + 4096, 8192, 4096, 4096, 2048,
                                           bf1 + 4096, nullptr, nullptr, 1, 0);

  // 8) FWHT(8192) in-place on FF
  fwht_ip<8192><<<4096, 256, 0, stream>>>(FFb);

  // 9) FF2 (unsplit, K=8192) + bias + residual(X1 in d_out) -> d_out (f32)
  cvt_k<<<8192, 256, 0, stream>>>(Qf2, Wf2);
  gemm256<<<dim3(16,16), 512, 0, stream>>>(FFb, Wf2, sf2, Xout, 2048, 4096, 2048, 8192,
                                           bf2, Xout, nullptr, 0, 1);
}

// Round 6
// 1225.802 us; speedup vs baseline: 1.0562x; 1.0058x over previous
//
#include <hip/hip_runtime.h>
#include <cstdint>
#include <cstddef>

typedef unsigned short u16;
typedef unsigned int   u32;
typedef __bf16 bf16x8 __attribute__((ext_vector_type(8)));
typedef float  f32x4  __attribute__((ext_vector_type(4)));

// ---------- bf16 helpers (RNE) ----------
__device__ __forceinline__ float bf2f(u16 u) {
  union { u32 i; float f; } v; v.i = ((u32)u) << 16; return v.f;
}
__device__ __forceinline__ u16 f2bf(float f) {
  union { float f; u32 i; } v; v.f = f;
  u32 r = v.i + 0x7fffu + ((v.i >> 16) & 1u);
  return (u16)(r >> 16);
}
__device__ __forceinline__ void unpack8(uint4 raw, float* v) {
  v[0]=bf2f(raw.x&0xffff); v[1]=bf2f(raw.x>>16);
  v[2]=bf2f(raw.y&0xffff); v[3]=bf2f(raw.y>>16);
  v[4]=bf2f(raw.z&0xffff); v[5]=bf2f(raw.z>>16);
  v[6]=bf2f(raw.w&0xffff); v[7]=bf2f(raw.w>>16);
}
__device__ __forceinline__ uint4 pack8(const float* v) {
  uint4 r;
  r.x = (u32)f2bf(v[0]) | ((u32)f2bf(v[1])<<16);
  r.y = (u32)f2bf(v[2]) | ((u32)f2bf(v[3])<<16);
  r.z = (u32)f2bf(v[4]) | ((u32)f2bf(v[5])<<16);
  r.w = (u32)f2bf(v[6]) | ((u32)f2bf(v[7])<<16);
  return r;
}
__device__ __forceinline__ void gload16(const void* g, void* l) {
  __builtin_amdgcn_global_load_lds((const __attribute__((address_space(1))) void*)g,
                                   (__attribute__((address_space(3))) void*)l, 16, 0, 0);
}
// attn LDS chunk swizzle: row-dependent XOR on the 16B-chunk index.
__device__ __forceinline__ int swz8(int row) { return ((row >> 3) ^ row) & 7; }

// ---------- load 8 consecutive elems as f32, from f32 or bf16 source ----------
template<typename T>
__device__ __forceinline__ void load8(const T* p, float* v);
template<> __device__ __forceinline__ void load8<float>(const float* p, float* v) {
  const float4 a = ((const float4*)p)[0];
  const float4 b = ((const float4*)p)[1];
  v[0]=a.x; v[1]=a.y; v[2]=a.z; v[3]=a.w;
  v[4]=b.x; v[5]=b.y; v[6]=b.z; v[7]=b.w;
}
template<> __device__ __forceinline__ void load8<u16>(const u16* p, float* v) {
  unpack8(*(const uint4*)p, v);
}

// ---------- int32 (|q|<=127) -> bf16, EXACT (high-16 truncation of f32) ----------
__global__ __launch_bounds__(256) void cvt_k(const int* __restrict__ Q, u16* __restrict__ W) {
  const size_t i = ((size_t)blockIdx.x * 256 + threadIdx.x) * 8;
  const int4 a = *(const int4*)(Q + i);
  const int4 b = *(const int4*)(Q + i + 4);
  union { float f; u32 u; } c;
  uint4 r;
  u32 t;
  c.f = (float)a.x; t = c.u >> 16; c.f = (float)a.y; r.x = t | (c.u & 0xffff0000u);
  c.f = (float)a.z; t = c.u >> 16; c.f = (float)a.w; r.y = t | (c.u & 0xffff0000u);
  c.f = (float)b.x; t = c.u >> 16; c.f = (float)b.y; r.z = t | (c.u & 0xffff0000u);
  c.f = (float)b.z; t = c.u >> 16; c.f = (float)b.w; r.w = t | (c.u & 0xffff0000u);
  *(uint4*)(W + i) = r;
}

// ---------- concat 3x2048 f32 scales ----------
__global__ __launch_bounds__(256) void scat_k(const float* __restrict__ a,
    const float* __restrict__ b, const float* __restrict__ c, float* __restrict__ o) {
  const int i = blockIdx.x * 256 + threadIdx.x;   // 24*256 = 6144
  o[i] = (i < 2048) ? a[i] : (i < 4096 ? b[i - 2048] : c[i - 4096]);
}

// ---------- LayerNorm + FWHT(2048), one row per block; out bf16 ----------
template<typename T>
__global__ __launch_bounds__(256) void ln_fwht_k(const T* __restrict__ X,
    const float* __restrict__ G, const float* __restrict__ Bt, u16* __restrict__ O) {
  __shared__ float buf[2048];
  __shared__ float red[8];
  const int tid = threadIdx.x;
  const int lane = tid & 63, wave = tid >> 6;
  const size_t base = (size_t)blockIdx.x * 2048;
  float v[8]; load8(X + base + tid*8, v);
  float s = 0.f, s2 = 0.f;
  for (int j = 0; j < 8; ++j) { s += v[j]; s2 += v[j]*v[j]; }
  for (int m = 1; m < 64; m <<= 1) { s += __shfl_xor(s, m, 64); s2 += __shfl_xor(s2, m, 64); }
  if (lane == 0) { red[wave] = s; red[4 + wave] = s2; }
  __syncthreads();
  s  = red[0] + red[1] + red[2] + red[3];
  s2 = red[4] + red[5] + red[6] + red[7];
  const float mu = s * (1.f/2048.f);
  const float rstd = rsqrtf(s2 * (1.f/2048.f) - mu*mu + 1e-5f);
  float g[8], bb[8];
  load8(G + tid*8, g); load8(Bt + tid*8, bb);
  for (int j = 0; j < 8; ++j) buf[tid*8 + j] = (v[j] - mu) * rstd * g[j] + bb[j];
  __syncthreads();
  for (int h = 1; h < 2048; h <<= 1) {
    for (int p = 0; p < 4; ++p) {
      const int idx = p*256 + tid;
      const int i = ((idx & ~(h-1)) << 1) | (idx & (h-1));
      const float a = buf[i], c = buf[i + h];
      buf[i] = a + c; buf[i + h] = a - c;
    }
    __syncthreads();
  }
  float o[8];
  for (int j = 0; j < 8; ++j) o[j] = buf[tid*8 + j] * 0.02209708691207961f; // 1/sqrt(2048)
  *(uint4*)&O[base + tid*8] = pack8(o);
}

// ---------- in-place FWHT<N> on bf16 rows ----------
template<int N>
__global__ __launch_bounds__(256) void fwht_ip(u16* __restrict__ D) {
  __shared__ float buf[N];
  const int tid = threadIdx.x;
  const size_t base = (size_t)blockIdx.x * N;
  constexpr int V8 = N / (8*256);
  for (int i = 0; i < V8; ++i) {
    uint4 raw = *(const uint4*)&D[base + (i*256 + tid)*8];
    float v[8]; unpack8(raw, v);
    for (int j = 0; j < 8; ++j) buf[(i*256 + tid)*8 + j] = v[j];
  }
  __syncthreads();
  constexpr int PAIRS = N / 2 / 256;
  for (int h = 1; h < N; h <<= 1) {
    for (int p = 0; p < PAIRS; ++p) {
      const int idx = p*256 + tid;
      const int i = ((idx & ~(h-1)) << 1) | (idx & (h-1));
      const float a = buf[i], c = buf[i + h];
      buf[i] = a + c; buf[i + h] = a - c;
    }
    __syncthreads();
  }
  const float sc = rsqrtf((float)N);
  for (int i = 0; i < V8; ++i) {
    float v[8];
    for (int j = 0; j < 8; ++j) v[j] = buf[(i*256 + tid)*8 + j] * sc;
    *(uint4*)&D[base + (i*256 + tid)*8] = pack8(v);
  }
}

// ---------- 256x128 triple-buffered GEMM, 2 MFMA-phases per K-tile ----------
// (unchanged from round 4/5 -- verified good; see journal)
__global__ __launch_bounds__(512, 1) void gemm256(
    const u16* __restrict__ A, const u16* __restrict__ Bw, const float* __restrict__ S,
    void* __restrict__ C, int ldc, int M, int N, int K,
    const float* __restrict__ bias, const float* __restrict__ resf,
    const u16* __restrict__ resb, int dogelu, int outf32)
{
  __shared__ alignas(16) u16 sA[3][256*64];
  __shared__ alignas(16) u16 sB[3][128*64];
  const int tid = threadIdx.x;
  const int lane = tid & 63, wave = tid >> 6;       // 8 waves
  const int quad = lane >> 4, l16 = lane & 15;
  const int wm = wave & 3, wn = wave >> 2;          // 4 M-waves x 2 N-waves
  const int nwg = gridDim.x * gridDim.y;
  int flat = blockIdx.y * gridDim.x + blockIdx.x;
  if ((nwg & 7) == 0) flat = (flat & 7) * (nwg >> 3) + (flat >> 3);
  const long tM = (long)(flat % gridDim.x) * 256;
  const long tN = (long)(flat / gridDim.x) * 128;

  const int rc = lane >> 3;
  const int cswz = ((lane & 7) ^ rc) * 8;
  const u16* Ab = A  + (size_t)(tM + rc) * K + cswz;
  const u16* Bb = Bw + (size_t)(tN + rc) * K + cswz;

  f32x4 acc[4][4] = {};
  const int ntk = K >> 6;

  auto stageA = [&](int buf, int k0, int i) {
    const int chunk = i*8 + wave;
    gload16(Ab + (size_t)(chunk*8)*K + k0, &sA[buf][chunk*512]);
  };
  auto stageB = [&](int buf, int k0, int i) {
    const int chunk = i*8 + wave;
    gload16(Bb + (size_t)(chunk*8)*K + k0, &sB[buf][chunk*512]);
  };

  stageA(0, 0, 0); stageA(0, 0, 1); stageA(0, 0, 2); stageA(0, 0, 3);
  stageB(0, 0, 0); stageB(0, 0, 1);
  if (ntk > 1) {
    stageA(1, 64, 0); stageA(1, 64, 1); stageA(1, 64, 2); stageA(1, 64, 3);
    stageB(1, 64, 0); stageB(1, 64, 1);
  }
  asm volatile("s_waitcnt vmcnt(6)" ::: "memory");   // tile 0 complete
  __builtin_amdgcn_s_barrier();
  __builtin_amdgcn_sched_barrier(0);

  for (int t = 0; t < ntk; ++t) {
    const int buf = t % 3, nb = (t + 2) % 3;
    const bool more = (t + 2) < ntk;
    const int k2 = (t + 2) << 6;
    bf16x8 af[4], bq[4];
#pragma unroll
    for (int ks = 0; ks < 2; ++ks) {
      const int oc = ks*4 + quad;
#pragma unroll
      for (int mt = 0; mt < 4; ++mt)
        af[mt] = *(const bf16x8*)&sA[buf][(wm*64 + mt*16 + l16)*64 + (oc ^ (l16 & 7))*8];
#pragma unroll
      for (int nt = 0; nt < 4; ++nt)
        bq[nt] = *(const bf16x8*)&sB[buf][(wn*64 + nt*16 + l16)*64 + (oc ^ (l16 & 7))*8];
      if (more) {
        if (ks == 0) { stageA(nb, k2, 0); stageA(nb, k2, 1); stageB(nb, k2, 0); }
        else         { stageA(nb, k2, 2); stageA(nb, k2, 3); stageB(nb, k2, 1); }
      }
      if (ks == 1 && t + 1 < ntk) {
        if (more) asm volatile("s_waitcnt vmcnt(6)" ::: "memory");
        else      asm volatile("s_waitcnt vmcnt(0)" ::: "memory");
      }
      __builtin_amdgcn_s_barrier();
      __builtin_amdgcn_sched_barrier(0);
      __builtin_amdgcn_s_setprio(1);
#pragma unroll
      for (int mt = 0; mt < 4; ++mt)
#pragma unroll
        for (int nt = 0; nt < 4; ++nt)
          acc[mt][nt] = __builtin_amdgcn_mfma_f32_16x16x32_bf16(af[mt], bq[nt], acc[mt][nt], 0, 0, 0);
      __builtin_amdgcn_s_setprio(0);
      __builtin_amdgcn_s_barrier();
      __builtin_amdgcn_sched_barrier(0);
    }
  }

#pragma unroll
  for (int in = 0; in < 4; ++in) {
    const long col = tN + wn*64 + in*16 + l16;
    const float sc = S[col];
    const float bv = bias ? bias[col] : 0.f;
#pragma unroll
    for (int im = 0; im < 4; ++im) {
      const long row0 = tM + wm*64 + im*16 + quad*4;
#pragma unroll
      for (int r = 0; r < 4; ++r) {
        float v = acc[im][in][r] * sc + bv;
        if (dogelu) v = 0.5f * v * (1.f + erff(v * 0.7071067811865475f));
        const size_t off = (size_t)(row0 + r)*ldc + col;
        if (resf) v += resf[off];
        if (resb) v += bf2f(resb[off]);
        if (outf32) ((float*)C)[off] = v;
        else        ((u16*)C)[off]   = f2bf(v);
      }
    }
  }
}

// ---------- fused MFMA attention, spill-free geometry ----------
// 64 Q-rows per block (grid 16x64), 4 waves x 16 Q-rows each.
// Per-wave regs: aq[4]=16 + sf[8]=32 + oacc[8]=32 + m/l=8 ~= 90 -> no scratch
// (round-5's 32-rows/wave held ~176 live f32 at 128 VGPR -> spill traffic was
// 384MB FETCH / 79MB WRITE and 100% of the slowdown).
// LDS 48 KiB (sKV 32K + sP 16K) -> 3 blocks/CU.
// XCD-chunked swizzle clusters the 16 qt-blocks sharing each bh's K/V.
__global__ __launch_bounds__(256, 3) void attn_k(const u16* __restrict__ QKV, u16* __restrict__ O)
{
  __shared__ alignas(16) u16 sKV[16384];  // K tile [128][128] -> V^T tile [d=128][kv=128]
  __shared__ alignas(16) u16 sP[8192];    // Q tile [64][128] at start, then per-wave P [16][128]
  const int tid = threadIdx.x;
  const int lane = tid & 63, wave = tid >> 6;
  const int quad = lane >> 4, l16 = lane & 15;
  const int nwg = gridDim.x * gridDim.y;  // 1024, %8==0 -> bijective
  int flat = blockIdx.y * gridDim.x + blockIdx.x;
  flat = (flat & 7) * (nwg >> 3) + (flat >> 3);
  const int qt = flat & 15;         // 0..15 (64-row Q tile)
  const int bh = flat >> 4;         // 0..63
  const int b = bh >> 4, h = bh & 15;
  const size_t rb = (size_t)b * 1024;
  const u16* Qg = QKV + (rb + (size_t)qt*64)*6144 + h*128;
  const u16* Kg = QKV + rb*6144 + 2048 + h*128;
  const u16* Vg = QKV + rb*6144 + 4096 + h*128;

  // Q stage: 16 chunks x 1KiB (4 rows each), swizzled global source (rule 21)
  for (int c = 0; c < 4; ++c) {
    const int chunk = c*4 + wave;
    const int r = chunk*4 + quad;
    gload16(Qg + (size_t)r*6144 + (l16 ^ swz8(r))*8, &sP[chunk*512]);
  }
  __syncthreads();
  bf16x8 aq[4];
#pragma unroll
  for (int kk = 0; kk < 4; ++kk) {
    const int row = wave*16 + l16;
    aq[kk] = *(const bf16x8*)&sP[row*128 + ((kk*4 + quad) ^ swz8(row))*8];
  }

  float mrun[4], lrun[4];
  f32x4 oacc[8] = {};
#pragma unroll
  for (int r = 0; r < 4; ++r) { mrun[r] = -1e30f; lrun[r] = 0.f; }

  for (int kt = 0; kt < 8; ++kt) {
    __syncthreads();                      // prev PV done reading sKV
    for (int c = 0; c < 8; ++c) {
      const int chunk = c*4 + wave;
      const int r = chunk*4 + quad;
      gload16(Kg + (size_t)(kt*128 + r)*6144 + (l16 ^ swz8(r))*8, &sKV[chunk*512]);
    }
    __syncthreads();
    f32x4 sf[8] = {};
#pragma unroll
    for (int kk = 0; kk < 4; ++kk)
#pragma unroll
      for (int jn = 0; jn < 8; ++jn) {
        const int rk = jn*16 + l16;
        const bf16x8 bk = *(const bf16x8*)&sKV[rk*128 + ((kk*4 + quad) ^ swz8(rk))*8];
        sf[jn] = __builtin_amdgcn_mfma_f32_16x16x32_bf16(aq[kk], bk, sf[jn], 0, 0, 0);
      }
    const float scale = 0.08838834764831845f;   // 1/sqrt(128)
#pragma unroll
    for (int r = 0; r < 4; ++r) {
      float mx = -1e30f;
      for (int jn = 0; jn < 8; ++jn) mx = fmaxf(mx, sf[jn][r] * scale);
      for (int m = 1; m < 16; m <<= 1) mx = fmaxf(mx, __shfl_xor(mx, m, 64));
      const float mold = mrun[r];
      const float mnew = fmaxf(mold, mx);
      const float alpha = __expf(mold - mnew);
      float ls = 0.f;
      const int rl = quad*4 + r;
      for (int jn = 0; jn < 8; ++jn) {
        const float p = __expf(sf[jn][r] * scale - mnew);
        ls += p;
        sP[wave*2048 + rl*128 + (((jn*2 + (l16 >> 3)) ^ swz8(rl))*8 | (l16 & 7))] = f2bf(p);
      }
      for (int m = 1; m < 16; m <<= 1) ls += __shfl_xor(ls, m, 64);
      lrun[r] = lrun[r]*alpha + ls;
      mrun[r] = mnew;
      for (int od = 0; od < 8; ++od) oacc[od][r] *= alpha;
    }
    __syncthreads();
    // V^T tile: pair-rows (short reg lifetime), packed b32 swizzled writes
#pragma unroll
    for (int c = 0; c < 4; ++c) {
      const int task = c*256 + tid;       // 0..1023
      const int kv = (task >> 4) * 2;
      const int d0 = (task & 15) * 8;
      const uint4 ra = *(const uint4*)(Vg + (size_t)(kt*128 + kv    )*6144 + d0);
      const uint4 rcx = *(const uint4*)(Vg + (size_t)(kt*128 + kv + 1)*6144 + d0);
      const int cc = kv >> 3;
      const u16* pa = (const u16*)&ra;
      const u16* pb = (const u16*)&rcx;
#pragma unroll
      for (int j = 0; j < 8; ++j) {
        const int row = d0 + j;
        const int col = ((cc ^ swz8(row))*8) | (kv & 7);
        *(u32*)&sKV[row*128 + col] = (u32)pa[j] | ((u32)pb[j] << 16);
      }
    }
    __syncthreads();
#pragma unroll
    for (int kk = 0; kk < 4; ++kk) {
      const bf16x8 ap = *(const bf16x8*)&sP[wave*2048 + l16*128 + ((kk*4 + quad) ^ swz8(l16))*8];
#pragma unroll
      for (int od = 0; od < 8; ++od) {
        const int rv = od*16 + l16;
        const bf16x8 bv = *(const bf16x8*)&sKV[rv*128 + ((kk*4 + quad) ^ swz8(rv))*8];
        oacc[od] = __builtin_amdgcn_mfma_f32_16x16x32_bf16(ap, bv, oacc[od], 0, 0, 0);
      }
    }
  }
#pragma unroll
  for (int r = 0; r < 4; ++r) {
    const float inv = 1.f / lrun[r];
    const size_t row = rb + (size_t)qt*64 + wave*16 + quad*4 + r;
    for (int od = 0; od < 8; ++od)
      O[row*2048 + h*128 + od*16 + l16] = f2bf(oacc[od][r] * inv);
  }
}

extern "C" void kernel_launch(void* const* d_in, const int* in_sizes, int n_in,
                              void* d_out, int out_size, void* d_ws, size_t ws_size,
                              hipStream_t stream) {
  const float* x    = (const float*)d_in[0];
  const float* ln1g = (const float*)d_in[1];
  const float* ln1b = (const float*)d_in[2];
  const float* ln2g = (const float*)d_in[3];
  const float* ln2b = (const float*)d_in[4];
  const int* Qq  = (const int*)d_in[5];  const float* sq  = (const float*)d_in[6];
  const int* Qk  = (const int*)d_in[7];  const float* sk  = (const float*)d_in[8];
  const int* Qv  = (const int*)d_in[9];  const float* sv  = (const float*)d_in[10];
  const int* Qo  = (const int*)d_in[11]; const float* so  = (const float*)d_in[12];
  const int* Qf1 = (const int*)d_in[13]; const float* sf1 = (const float*)d_in[14];
  const float* bf1 = (const float*)d_in[15];
  const int* Qf2 = (const int*)d_in[16]; const float* sf2 = (const float*)d_in[17];
  const float* bf2 = (const float*)d_in[18];

  // arena (u16 elems), 96 MiB, byte map:
  //   XH   [ 0,16) MiB : XH1 -> ATT -> XH2
  //   Wq   [16,40) MiB : QKV weights concat [6144,2048] bf16 (24 MiB)
  //   Wsl  [16,32) MiB : rotating weight slot (Qo 8 MiB, FF1 halves 16 MiB)
  //   QKV  [40,88) MiB : [4096,6144] bf16
  //   FF   [32,96) MiB : [4096,8192] bf16 (after attn; QKV dead)
  //   Wf2  [ 0,32) MiB : FF2 weight [2048,8192] bf16 (XH & Wsl dead by then)
  //   Scat [88, +24KiB): concat scales f32[6144]
  u16* XH   = (u16*)d_ws;
  u16* Wq   = XH + 8388608;
  u16* Wsl  = XH + 8388608;
  u16* QKVb = XH + 20971520;
  u16* FFb  = XH + 16777216;
  u16* Wf2  = XH;
  float* Scat = (float*)(XH + 46137344);
  float* Xout = (float*)d_out;
  if (ws_size < (size_t)100663296) return;   // guard (signals via poisoned d_out)

  // 1) LN1 + FWHT (f32 x -> bf16 XH1)
  ln_fwht_k<float><<<4096, 256, 0, stream>>>(x, ln1g, ln1b, XH);

  // 2) fused QKV projection: one N=6144 GEMM (concat weights + scales)
  cvt_k<<<2048, 256, 0, stream>>>(Qq, Wq);
  cvt_k<<<2048, 256, 0, stream>>>(Qk, Wq + 4194304);
  cvt_k<<<2048, 256, 0, stream>>>(Qv, Wq + 8388608);
  scat_k<<<24, 256, 0, stream>>>(sq, sk, sv, Scat);
  gemm256<<<dim3(16,48), 512, 0, stream>>>(XH, Wq, Scat, QKVb, 6144, 4096, 6144, 2048,
                                           nullptr, nullptr, nullptr, 0, 0);

  // 3) attention -> ATT (XH region); 64-row Q tiles
  attn_k<<<dim3(16, 64), 256, 0, stream>>>(QKVb, XH);

  // 4) FWHT(2048) in-place on ATT
  fwht_ip<2048><<<4096, 256, 0, stream>>>(XH);

  // 5) O-proj + residual(x, f32) -> X1 = d_out (f32)
  cvt_k<<<2048, 256, 0, stream>>>(Qo, Wsl);
  gemm256<<<dim3(16,16), 512, 0, stream>>>(XH, Wsl, so, Xout, 2048, 4096, 2048, 2048,
                                           nullptr, x, nullptr, 0, 1);

  // 6) LN2 + FWHT: X1 (f32, in d_out) -> XH2
  ln_fwht_k<float><<<4096, 256, 0, stream>>>(Xout, ln2g, ln2b, XH);

  // 7) FF1 + bias + exact GELU -> FF (bf16), split along N (weight half fits Wsl)
  cvt_k<<<4096, 256, 0, stream>>>(Qf1, Wsl);
  gemm256<<<dim3(16,32), 512, 0, stream>>>(XH, Wsl, sf1,        FFb + 0,    8192, 4096, 4096, 2048,
                                           bf1,        nullptr, nullptr, 1, 0);
  cvt_k<<<4096, 256, 0, stream>>>(Qf1 + (size_t)4096*2048, Wsl);
  gemm256<<<dim3(16,32), 512, 0, stream>>>(XH, Wsl, sf1 + 4096, FFb + 4096, 8192, 4096, 4096, 2048,
                                           bf1 + 4096, nullptr, nullptr, 1, 0);

  // 8) FWHT(8192) in-place on FF
  fwht_ip<8192><<<4096, 256, 0, stream>>>(FFb);

  // 9) FF2 (unsplit, K=8192) + bias + residual(X1 in d_out) -> d_out (f32)
  cvt_k<<<8192, 256, 0, stream>>>(Qf2, Wf2);
  gemm256<<<dim3(16,16), 512, 0, stream>>>(FFb, Wf2, sf2, Xout, 2048, 4096, 2048, 8192,
                                           bf2, Xout, nullptr, 0, 1);
}

// Round 8
// 1202.186 us; speedup vs baseline: 1.0770x; 1.0196x over previous
//
#include <hip/hip_runtime.h>
#include <cstdint>
#include <cstddef>

typedef unsigned short u16;
typedef unsigned int   u32;
typedef __bf16 bf16x8 __attribute__((ext_vector_type(8)));
typedef float  f32x4  __attribute__((ext_vector_type(4)));

// ---------- bf16 helpers (RNE) ----------
__device__ __forceinline__ float bf2f(u16 u) {
  union { u32 i; float f; } v; v.i = ((u32)u) << 16; return v.f;
}
__device__ __forceinline__ u16 f2bf(float f) {
  union { float f; u32 i; } v; v.f = f;
  u32 r = v.i + 0x7fffu + ((v.i >> 16) & 1u);
  return (u16)(r >> 16);
}
__device__ __forceinline__ void unpack8(uint4 raw, float* v) {
  v[0]=bf2f(raw.x&0xffff); v[1]=bf2f(raw.x>>16);
  v[2]=bf2f(raw.y&0xffff); v[3]=bf2f(raw.y>>16);
  v[4]=bf2f(raw.z&0xffff); v[5]=bf2f(raw.z>>16);
  v[6]=bf2f(raw.w&0xffff); v[7]=bf2f(raw.w>>16);
}
__device__ __forceinline__ uint4 pack8(const float* v) {
  uint4 r;
  r.x = (u32)f2bf(v[0]) | ((u32)f2bf(v[1])<<16);
  r.y = (u32)f2bf(v[2]) | ((u32)f2bf(v[3])<<16);
  r.z = (u32)f2bf(v[4]) | ((u32)f2bf(v[5])<<16);
  r.w = (u32)f2bf(v[6]) | ((u32)f2bf(v[7])<<16);
  return r;
}
__device__ __forceinline__ void gload16(const void* g, void* l) {
  __builtin_amdgcn_global_load_lds((const __attribute__((address_space(1))) void*)g,
                                   (__attribute__((address_space(3))) void*)l, 16, 0, 0);
}
// attn LDS chunk swizzle: row-dependent XOR on the 16B-chunk index.
__device__ __forceinline__ int swz8(int row) { return ((row >> 3) ^ row) & 7; }

// ---------- load 8 consecutive elems as f32, from f32 or bf16 source ----------
template<typename T>
__device__ __forceinline__ void load8(const T* p, float* v);
template<> __device__ __forceinline__ void load8<float>(const float* p, float* v) {
  const float4 a = ((const float4*)p)[0];
  const float4 b = ((const float4*)p)[1];
  v[0]=a.x; v[1]=a.y; v[2]=a.z; v[3]=a.w;
  v[4]=b.x; v[5]=b.y; v[6]=b.z; v[7]=b.w;
}
template<> __device__ __forceinline__ void load8<u16>(const u16* p, float* v) {
  unpack8(*(const uint4*)p, v);
}

// ---------- int32 (|q|<=127) -> bf16, EXACT (high-16 truncation of f32) ----------
__global__ __launch_bounds__(256) void cvt_k(const int* __restrict__ Q, u16* __restrict__ W) {
  const size_t i = ((size_t)blockIdx.x * 256 + threadIdx.x) * 8;
  const int4 a = *(const int4*)(Q + i);
  const int4 b = *(const int4*)(Q + i + 4);
  union { float f; u32 u; } c;
  uint4 r;
  u32 t;
  c.f = (float)a.x; t = c.u >> 16; c.f = (float)a.y; r.x = t | (c.u & 0xffff0000u);
  c.f = (float)a.z; t = c.u >> 16; c.f = (float)a.w; r.y = t | (c.u & 0xffff0000u);
  c.f = (float)b.x; t = c.u >> 16; c.f = (float)b.y; r.z = t | (c.u & 0xffff0000u);
  c.f = (float)b.z; t = c.u >> 16; c.f = (float)b.w; r.w = t | (c.u & 0xffff0000u);
  *(uint4*)(W + i) = r;
}

// ---------- concat 3x2048 f32 scales ----------
__global__ __launch_bounds__(256) void scat_k(const float* __restrict__ a,
    const float* __restrict__ b, const float* __restrict__ c, float* __restrict__ o) {
  const int i = blockIdx.x * 256 + threadIdx.x;   // 24*256 = 6144
  o[i] = (i < 2048) ? a[i] : (i < 4096 ? b[i - 2048] : c[i - 4096]);
}

// ---------- LayerNorm + FWHT(2048), one row per block; out bf16 ----------
template<typename T>
__global__ __launch_bounds__(256) void ln_fwht_k(const T* __restrict__ X,
    const float* __restrict__ G, const float* __restrict__ Bt, u16* __restrict__ O) {
  __shared__ float buf[2048];
  __shared__ float red[8];
  const int tid = threadIdx.x;
  const int lane = tid & 63, wave = tid >> 6;
  const size_t base = (size_t)blockIdx.x * 2048;
  float v[8]; load8(X + base + tid*8, v);
  float s = 0.f, s2 = 0.f;
  for (int j = 0; j < 8; ++j) { s += v[j]; s2 += v[j]*v[j]; }
  for (int m = 1; m < 64; m <<= 1) { s += __shfl_xor(s, m, 64); s2 += __shfl_xor(s2, m, 64); }
  if (lane == 0) { red[wave] = s; red[4 + wave] = s2; }
  __syncthreads();
  s  = red[0] + red[1] + red[2] + red[3];
  s2 = red[4] + red[5] + red[6] + red[7];
  const float mu = s * (1.f/2048.f);
  const float rstd = rsqrtf(s2 * (1.f/2048.f) - mu*mu + 1e-5f);
  float g[8], bb[8];
  load8(G + tid*8, g); load8(Bt + tid*8, bb);
  for (int j = 0; j < 8; ++j) buf[tid*8 + j] = (v[j] - mu) * rstd * g[j] + bb[j];
  __syncthreads();
  for (int h = 1; h < 2048; h <<= 1) {
    for (int p = 0; p < 4; ++p) {
      const int idx = p*256 + tid;
      const int i = ((idx & ~(h-1)) << 1) | (idx & (h-1));
      const float a = buf[i], c = buf[i + h];
      buf[i] = a + c; buf[i + h] = a - c;
    }
    __syncthreads();
  }
  float o[8];
  for (int j = 0; j < 8; ++j) o[j] = buf[tid*8 + j] * 0.02209708691207961f; // 1/sqrt(2048)
  *(uint4*)&O[base + tid*8] = pack8(o);
}

// ---------- in-place FWHT<N> on bf16 rows ----------
template<int N>
__global__ __launch_bounds__(256) void fwht_ip(u16* __restrict__ D) {
  __shared__ float buf[N];
  const int tid = threadIdx.x;
  const size_t base = (size_t)blockIdx.x * N;
  constexpr int V8 = N / (8*256);
  for (int i = 0; i < V8; ++i) {
    uint4 raw = *(const uint4*)&D[base + (i*256 + tid)*8];
    float v[8]; unpack8(raw, v);
    for (int j = 0; j < 8; ++j) buf[(i*256 + tid)*8 + j] = v[j];
  }
  __syncthreads();
  constexpr int PAIRS = N / 2 / 256;
  for (int h = 1; h < N; h <<= 1) {
    for (int p = 0; p < PAIRS; ++p) {
      const int idx = p*256 + tid;
      const int i = ((idx & ~(h-1)) << 1) | (idx & (h-1));
      const float a = buf[i], c = buf[i + h];
      buf[i] = a + c; buf[i + h] = a - c;
    }
    __syncthreads();
  }
  const float sc = rsqrtf((float)N);
  for (int i = 0; i < V8; ++i) {
    float v[8];
    for (int j = 0; j < 8; ++j) v[j] = buf[(i*256 + tid)*8 + j] * sc;
    *(uint4*)&D[base + (i*256 + tid)*8] = pack8(v);
  }
}

// ---------- 256x128 triple-buffered GEMM, 2 MFMA-phases per K-tile ----------
// (unchanged -- verified good; see journal)
__global__ __launch_bounds__(512, 1) void gemm256(
    const u16* __restrict__ A, const u16* __restrict__ Bw, const float* __restrict__ S,
    void* __restrict__ C, int ldc, int M, int N, int K,
    const float* __restrict__ bias, const float* __restrict__ resf,
    const u16* __restrict__ resb, int dogelu, int outf32)
{
  __shared__ alignas(16) u16 sA[3][256*64];
  __shared__ alignas(16) u16 sB[3][128*64];
  const int tid = threadIdx.x;
  const int lane = tid & 63, wave = tid >> 6;       // 8 waves
  const int quad = lane >> 4, l16 = lane & 15;
  const int wm = wave & 3, wn = wave >> 2;          // 4 M-waves x 2 N-waves
  const int nwg = gridDim.x * gridDim.y;
  int flat = blockIdx.y * gridDim.x + blockIdx.x;
  if ((nwg & 7) == 0) flat = (flat & 7) * (nwg >> 3) + (flat >> 3);
  const long tM = (long)(flat % gridDim.x) * 256;
  const long tN = (long)(flat / gridDim.x) * 128;

  const int rc = lane >> 3;
  const int cswz = ((lane & 7) ^ rc) * 8;
  const u16* Ab = A  + (size_t)(tM + rc) * K + cswz;
  const u16* Bb = Bw + (size_t)(tN + rc) * K + cswz;

  f32x4 acc[4][4] = {};
  const int ntk = K >> 6;

  auto stageA = [&](int buf, int k0, int i) {
    const int chunk = i*8 + wave;
    gload16(Ab + (size_t)(chunk*8)*K + k0, &sA[buf][chunk*512]);
  };
  auto stageB = [&](int buf, int k0, int i) {
    const int chunk = i*8 + wave;
    gload16(Bb + (size_t)(chunk*8)*K + k0, &sB[buf][chunk*512]);
  };

  stageA(0, 0, 0); stageA(0, 0, 1); stageA(0, 0, 2); stageA(0, 0, 3);
  stageB(0, 0, 0); stageB(0, 0, 1);
  if (ntk > 1) {
    stageA(1, 64, 0); stageA(1, 64, 1); stageA(1, 64, 2); stageA(1, 64, 3);
    stageB(1, 64, 0); stageB(1, 64, 1);
  }
  asm volatile("s_waitcnt vmcnt(6)" ::: "memory");   // tile 0 complete
  __builtin_amdgcn_s_barrier();
  __builtin_amdgcn_sched_barrier(0);

  for (int t = 0; t < ntk; ++t) {
    const int buf = t % 3, nb = (t + 2) % 3;
    const bool more = (t + 2) < ntk;
    const int k2 = (t + 2) << 6;
    bf16x8 af[4], bq[4];
#pragma unroll
    for (int ks = 0; ks < 2; ++ks) {
      const int oc = ks*4 + quad;
#pragma unroll
      for (int mt = 0; mt < 4; ++mt)
        af[mt] = *(const bf16x8*)&sA[buf][(wm*64 + mt*16 + l16)*64 + (oc ^ (l16 & 7))*8];
#pragma unroll
      for (int nt = 0; nt < 4; ++nt)
        bq[nt] = *(const bf16x8*)&sB[buf][(wn*64 + nt*16 + l16)*64 + (oc ^ (l16 & 7))*8];
      if (more) {
        if (ks == 0) { stageA(nb, k2, 0); stageA(nb, k2, 1); stageB(nb, k2, 0); }
        else         { stageA(nb, k2, 2); stageA(nb, k2, 3); stageB(nb, k2, 1); }
      }
      if (ks == 1 && t + 1 < ntk) {
        if (more) asm volatile("s_waitcnt vmcnt(6)" ::: "memory");
        else      asm volatile("s_waitcnt vmcnt(0)" ::: "memory");
      }
      __builtin_amdgcn_s_barrier();
      __builtin_amdgcn_sched_barrier(0);
      __builtin_amdgcn_s_setprio(1);
#pragma unroll
      for (int mt = 0; mt < 4; ++mt)
#pragma unroll
        for (int nt = 0; nt < 4; ++nt)
          acc[mt][nt] = __builtin_amdgcn_mfma_f32_16x16x32_bf16(af[mt], bq[nt], acc[mt][nt], 0, 0, 0);
      __builtin_amdgcn_s_setprio(0);
      __builtin_amdgcn_s_barrier();
      __builtin_amdgcn_sched_barrier(0);
    }
  }

#pragma unroll
  for (int in = 0; in < 4; ++in) {
    const long col = tN + wn*64 + in*16 + l16;
    const float sc = S[col];
    const float bv = bias ? bias[col] : 0.f;
#pragma unroll
    for (int im = 0; im < 4; ++im) {
      const long row0 = tM + wm*64 + im*16 + quad*4;
#pragma unroll
      for (int r = 0; r < 4; ++r) {
        float v = acc[im][in][r] * sc + bv;
        if (dogelu) v = 0.5f * v * (1.f + erff(v * 0.7071067811865475f));
        const size_t off = (size_t)(row0 + r)*ldc + col;
        if (resf) v += resf[off];
        if (resb) v += bf2f(resb[off]);
        if (outf32) ((float*)C)[off] = v;
        else        ((u16*)C)[off]   = f2bf(v);
      }
    }
  }
}

// ---------- fused MFMA attention: 128-row Q tiles, 8 waves x 16 rows ----------
// Round-7 NaN root cause: V^T staging used c<4 with 512 threads -> tasks
// 0..2047 -> kv up to 254 -> OOB LDS writes (col up to 255 > 127) corrupting
// sP. Correct task count is 64 kv-pairs x 16 d0-blocks = 1024 -> c<2.
// Geometry (round-6 post-mortem): attn is HBM-traffic-bound.
//  - 128-row Q blocks (grid 8x64) halve the K/V sharer count vs 64-row.
//  - 16 rows/wave keeps per-wave live regs ~90 -> no spill at VGPR<=128.
//  - all reg-array loops #pragma unroll'd (rule #20).
//  - 8 sharers per (b,h) on one XCD via bijective swizzle.
// LDS 64 KiB (sKV 32K + sP 32K) -> 2 blocks/CU.
__global__ __launch_bounds__(512, 4) void attn_k(const u16* __restrict__ QKV, u16* __restrict__ O)
{
  __shared__ alignas(16) u16 sKV[16384];  // K tile [128][128] -> V^T tile [d=128][kv=128]
  __shared__ alignas(16) u16 sP[16384];   // Q tile [128][128] at start, then per-wave P [16][128]
  const int tid = threadIdx.x;
  const int lane = tid & 63, wave = tid >> 6;      // 8 waves
  const int quad = lane >> 4, l16 = lane & 15;
  const int nwg = gridDim.x * gridDim.y;           // 512, %8==0 -> bijective
  int flat = blockIdx.y * gridDim.x + blockIdx.x;
  flat = (flat & 7) * (nwg >> 3) + (flat >> 3);
  const int qt = flat & 7;          // 0..7 (128-row Q tile)
  const int bh = flat >> 3;         // 0..63
  const int b = bh >> 4, h = bh & 15;
  const size_t rb = (size_t)b * 1024;
  const u16* Qg = QKV + (rb + (size_t)qt*128)*6144 + h*128;
  const u16* Kg = QKV + rb*6144 + 2048 + h*128;
  const u16* Vg = QKV + rb*6144 + 4096 + h*128;

  // Q stage: 32 chunks x 1KiB (4 rows each), swizzled global source (rule 21)
#pragma unroll
  for (int c = 0; c < 4; ++c) {
    const int chunk = c*8 + wave;
    const int r = chunk*4 + quad;
    gload16(Qg + (size_t)r*6144 + (l16 ^ swz8(r))*8, &sP[chunk*512]);
  }
  __syncthreads();
  bf16x8 aq[4];
#pragma unroll
  for (int kk = 0; kk < 4; ++kk) {
    const int row = wave*16 + l16;
    aq[kk] = *(const bf16x8*)&sP[row*128 + ((kk*4 + quad) ^ swz8(row))*8];
  }

  float mrun[4], lrun[4];
  f32x4 oacc[8] = {};
#pragma unroll
  for (int r = 0; r < 4; ++r) { mrun[r] = -1e30f; lrun[r] = 0.f; }

  for (int kt = 0; kt < 8; ++kt) {
    __syncthreads();                      // prev PV done reading sKV
#pragma unroll
    for (int c = 0; c < 4; ++c) {
      const int chunk = c*8 + wave;
      const int r = chunk*4 + quad;
      gload16(Kg + (size_t)(kt*128 + r)*6144 + (l16 ^ swz8(r))*8, &sKV[chunk*512]);
    }
    __syncthreads();
    f32x4 sf[8] = {};
#pragma unroll
    for (int kk = 0; kk < 4; ++kk)
#pragma unroll
      for (int jn = 0; jn < 8; ++jn) {
        const int rk = jn*16 + l16;
        const bf16x8 bk = *(const bf16x8*)&sKV[rk*128 + ((kk*4 + quad) ^ swz8(rk))*8];
        sf[jn] = __builtin_amdgcn_mfma_f32_16x16x32_bf16(aq[kk], bk, sf[jn], 0, 0, 0);
      }
    const float scale = 0.08838834764831845f;   // 1/sqrt(128)
#pragma unroll
    for (int r = 0; r < 4; ++r) {
      float mx = -1e30f;
#pragma unroll
      for (int jn = 0; jn < 8; ++jn) mx = fmaxf(mx, sf[jn][r] * scale);
#pragma unroll
      for (int m = 1; m < 16; m <<= 1) mx = fmaxf(mx, __shfl_xor(mx, m, 64));
      const float mold = mrun[r];
      const float mnew = fmaxf(mold, mx);
      const float alpha = __expf(mold - mnew);
      float ls = 0.f;
      const int rl = quad*4 + r;
#pragma unroll
      for (int jn = 0; jn < 8; ++jn) {
        const float p = __expf(sf[jn][r] * scale - mnew);
        ls += p;
        sP[wave*2048 + rl*128 + (((jn*2 + (l16 >> 3)) ^ swz8(rl))*8 | (l16 & 7))] = f2bf(p);
      }
#pragma unroll
      for (int m = 1; m < 16; m <<= 1) ls += __shfl_xor(ls, m, 64);
      lrun[r] = lrun[r]*alpha + ls;
      mrun[r] = mnew;
#pragma unroll
      for (int od = 0; od < 8; ++od) oacc[od][r] *= alpha;
    }
    __syncthreads();
    // V^T tile: 1024 tasks (64 kv-pairs x 16 d0-blocks) over 512 threads -> c<2
#pragma unroll
    for (int c = 0; c < 2; ++c) {
      const int task = c*512 + tid;       // 0..1023
      const int kv = (task >> 4) * 2;     // 0..126
      const int d0 = (task & 15) * 8;
      const uint4 ra  = *(const uint4*)(Vg + (size_t)(kt*128 + kv    )*6144 + d0);
      const uint4 rcx = *(const uint4*)(Vg + (size_t)(kt*128 + kv + 1)*6144 + d0);
      const int cc = kv >> 3;             // 0..15
      const u16* pa = (const u16*)&ra;
      const u16* pb = (const u16*)&rcx;
#pragma unroll
      for (int j = 0; j < 8; ++j) {
        const int row = d0 + j;
        const int col = ((cc ^ swz8(row))*8) | (kv & 7);
        *(u32*)&sKV[row*128 + col] = (u32)pa[j] | ((u32)pb[j] << 16);
      }
    }
    __syncthreads();
#pragma unroll
    for (int kk = 0; kk < 4; ++kk) {
      const bf16x8 ap = *(const bf16x8*)&sP[wave*2048 + l16*128 + ((kk*4 + quad) ^ swz8(l16))*8];
#pragma unroll
      for (int od = 0; od < 8; ++od) {
        const int rv = od*16 + l16;
        const bf16x8 bv = *(const bf16x8*)&sKV[rv*128 + ((kk*4 + quad) ^ swz8(rv))*8];
        oacc[od] = __builtin_amdgcn_mfma_f32_16x16x32_bf16(ap, bv, oacc[od], 0, 0, 0);
      }
    }
  }
#pragma unroll
  for (int r = 0; r < 4; ++r) {
    const float inv = 1.f / lrun[r];
    const size_t row = rb + (size_t)qt*128 + wave*16 + quad*4 + r;
#pragma unroll
    for (int od = 0; od < 8; ++od)
      O[row*2048 + h*128 + od*16 + l16] = f2bf(oacc[od][r] * inv);
  }
}

extern "C" void kernel_launch(void* const* d_in, const int* in_sizes, int n_in,
                              void* d_out, int out_size, void* d_ws, size_t ws_size,
                              hipStream_t stream) {
  const float* x    = (const float*)d_in[0];
  const float* ln1g = (const float*)d_in[1];
  const float* ln1b = (const float*)d_in[2];
  const float* ln2g = (const float*)d_in[3];
  const float* ln2b = (const float*)d_in[4];
  const int* Qq  = (const int*)d_in[5];  const float* sq  = (const float*)d_in[6];
  const int* Qk  = (const int*)d_in[7];  const float* sk  = (const float*)d_in[8];
  const int* Qv  = (const int*)d_in[9];  const float* sv  = (const float*)d_in[10];
  const int* Qo  = (const int*)d_in[11]; const float* so  = (const float*)d_in[12];
  const int* Qf1 = (const int*)d_in[13]; const float* sf1 = (const float*)d_in[14];
  const float* bf1 = (const float*)d_in[15];
  const int* Qf2 = (const int*)d_in[16]; const float* sf2 = (const float*)d_in[17];
  const float* bf2 = (const float*)d_in[18];

  // arena (u16 elems), 96 MiB, byte map:
  //   XH   [ 0,16) MiB : XH1 -> ATT -> XH2
  //   Wq   [16,40) MiB : QKV weights concat [6144,2048] bf16 (24 MiB)
  //   Wsl  [16,32) MiB : rotating weight slot (Qo 8 MiB, FF1 halves 16 MiB)
  //   QKV  [40,88) MiB : [4096,6144] bf16
  //   FF   [32,96) MiB : [4096,8192] bf16 (after attn; QKV dead)
  //   Wf2  [ 0,32) MiB : FF2 weight [2048,8192] bf16 (XH & Wsl dead by then)
  //   Scat [88, +24KiB): concat scales f32[6144]
  u16* XH   = (u16*)d_ws;
  u16* Wq   = XH + 8388608;
  u16* Wsl  = XH + 8388608;
  u16* QKVb = XH + 20971520;
  u16* FFb  = XH + 16777216;
  u16* Wf2  = XH;
  float* Scat = (float*)(XH + 46137344);
  float* Xout = (float*)d_out;
  if (ws_size < (size_t)100663296) return;   // guard (signals via poisoned d_out)

  // 1) LN1 + FWHT (f32 x -> bf16 XH1)
  ln_fwht_k<float><<<4096, 256, 0, stream>>>(x, ln1g, ln1b, XH);

  // 2) fused QKV projection: one N=6144 GEMM (concat weights + scales)
  cvt_k<<<2048, 256, 0, stream>>>(Qq, Wq);
  cvt_k<<<2048, 256, 0, stream>>>(Qk, Wq + 4194304);
  cvt_k<<<2048, 256, 0, stream>>>(Qv, Wq + 8388608);
  scat_k<<<24, 256, 0, stream>>>(sq, sk, sv, Scat);
  gemm256<<<dim3(16,48), 512, 0, stream>>>(XH, Wq, Scat, QKVb, 6144, 4096, 6144, 2048,
                                           nullptr, nullptr, nullptr, 0, 0);

  // 3) attention -> ATT (XH region); 128-row Q tiles, 8 waves
  attn_k<<<dim3(8, 64), 512, 0, stream>>>(QKVb, XH);

  // 4) FWHT(2048) in-place on ATT
  fwht_ip<2048><<<4096, 256, 0, stream>>>(XH);

  // 5) O-proj + residual(x, f32) -> X1 = d_out (f32)
  cvt_k<<<2048, 256, 0, stream>>>(Qo, Wsl);
  gemm256<<<dim3(16,16), 512, 0, stream>>>(XH, Wsl, so, Xout, 2048, 4096, 2048, 2048,
                                           nullptr, x, nullptr, 0, 1);

  // 6) LN2 + FWHT: X1 (f32, in d_out) -> XH2
  ln_fwht_k<float><<<4096, 256, 0, stream>>>(Xout, ln2g, ln2b, XH);

  // 7) FF1 + bias + exact GELU -> FF (bf16), split along N (weight half fits Wsl)
  cvt_k<<<4096, 256, 0, stream>>>(Qf1, Wsl);
  gemm256<<<dim3(16,32), 512, 0, stream>>>(XH, Wsl, sf1,        FFb + 0,    8192, 4096, 4096, 2048,
                                           bf1,        nullptr, nullptr, 1, 0);
  cvt_k<<<4096, 256, 0, stream>>>(Qf1 + (size_t)4096*2048, Wsl);
  gemm256<<<dim3(16,32), 512, 0, stream>>>(XH, Wsl, sf1 + 4096, FFb + 4096, 8192, 4096, 4096, 2048,
                                           bf1 + 4096, nullptr, nullptr, 1, 0);

  // 8) FWHT(8192) in-place on FF
  fwht_ip<8192><<<4096, 256, 0, stream>>>(FFb);

  // 9) FF2 (unsplit, K=8192) + bias + residual(X1 in d_out) -> d_out (f32)
  cvt_k<<<8192, 256, 0, stream>>>(Qf2, Wf2);
  gemm256<<<dim3(16,16), 512, 0, stream>>>(FFb, Wf2, sf2, Xout, 2048, 4096, 2048, 8192,
                                           bf2, Xout, nullptr, 0, 1);
}

// Round 9
// 1100.375 us; speedup vs baseline: 1.1766x; 1.0925x over previous
//
#include <hip/hip_runtime.h>
#include <cstdint>
#include <cstddef>

typedef unsigned short u16;
typedef unsigned int   u32;
typedef __bf16 bf16x8 __attribute__((ext_vector_type(8)));
typedef float  f32x4  __attribute__((ext_vector_type(4)));

// ---------- bf16 helpers (RNE) ----------
__device__ __forceinline__ float bf2f(u16 u) {
  union { u32 i; float f; } v; v.i = ((u32)u) << 16; return v.f;
}
__device__ __forceinline__ u16 f2bf(float f) {
  union { float f; u32 i; } v; v.f = f;
  u32 r = v.i + 0x7fffu + ((v.i >> 16) & 1u);
  return (u16)(r >> 16);
}
__device__ __forceinline__ void unpack8(uint4 raw, float* v) {
  v[0]=bf2f(raw.x&0xffff); v[1]=bf2f(raw.x>>16);
  v[2]=bf2f(raw.y&0xffff); v[3]=bf2f(raw.y>>16);
  v[4]=bf2f(raw.z&0xffff); v[5]=bf2f(raw.z>>16);
  v[6]=bf2f(raw.w&0xffff); v[7]=bf2f(raw.w>>16);
}
__device__ __forceinline__ uint4 pack8(const float* v) {
  uint4 r;
  r.x = (u32)f2bf(v[0]) | ((u32)f2bf(v[1])<<16);
  r.y = (u32)f2bf(v[2]) | ((u32)f2bf(v[3])<<16);
  r.z = (u32)f2bf(v[4]) | ((u32)f2bf(v[5])<<16);
  r.w = (u32)f2bf(v[6]) | ((u32)f2bf(v[7])<<16);
  return r;
}
__device__ __forceinline__ void gload16(const void* g, void* l) {
  __builtin_amdgcn_global_load_lds((const __attribute__((address_space(1))) void*)g,
                                   (__attribute__((address_space(3))) void*)l, 16, 0, 0);
}

// ---------- load 8 consecutive elems as f32, from f32 or bf16 source ----------
template<typename T>
__device__ __forceinline__ void load8(const T* p, float* v);
template<> __device__ __forceinline__ void load8<float>(const float* p, float* v) {
  const float4 a = ((const float4*)p)[0];
  const float4 b = ((const float4*)p)[1];
  v[0]=a.x; v[1]=a.y; v[2]=a.z; v[3]=a.w;
  v[4]=b.x; v[5]=b.y; v[6]=b.z; v[7]=b.w;
}
template<> __device__ __forceinline__ void load8<u16>(const u16* p, float* v) {
  unpack8(*(const uint4*)p, v);
}

// ---------- int32 (|q|<=127) -> bf16, EXACT (high-16 truncation of f32) ----------
__global__ __launch_bounds__(256) void cvt_k(const int* __restrict__ Q, u16* __restrict__ W) {
  const size_t i = ((size_t)blockIdx.x * 256 + threadIdx.x) * 8;
  const int4 a = *(const int4*)(Q + i);
  const int4 b = *(const int4*)(Q + i + 4);
  union { float f; u32 u; } c;
  uint4 r;
  u32 t;
  c.f = (float)a.x; t = c.u >> 16; c.f = (float)a.y; r.x = t | (c.u & 0xffff0000u);
  c.f = (float)a.z; t = c.u >> 16; c.f = (float)a.w; r.y = t | (c.u & 0xffff0000u);
  c.f = (float)b.x; t = c.u >> 16; c.f = (float)b.y; r.z = t | (c.u & 0xffff0000u);
  c.f = (float)b.z; t = c.u >> 16; c.f = (float)b.w; r.w = t | (c.u & 0xffff0000u);
  *(uint4*)(W + i) = r;
}

// ---------- concat 3x2048 f32 scales ----------
__global__ __launch_bounds__(256) void scat_k(const float* __restrict__ a,
    const float* __restrict__ b, const float* __restrict__ c, float* __restrict__ o) {
  const int i = blockIdx.x * 256 + threadIdx.x;   // 24*256 = 6144
  o[i] = (i < 2048) ? a[i] : (i < 4096 ? b[i - 2048] : c[i - 4096]);
}

// ---------- LayerNorm + FWHT(2048), one row per block; out bf16 ----------
template<typename T>
__global__ __launch_bounds__(256) void ln_fwht_k(const T* __restrict__ X,
    const float* __restrict__ G, const float* __restrict__ Bt, u16* __restrict__ O) {
  __shared__ float buf[2048];
  __shared__ float red[8];
  const int tid = threadIdx.x;
  const int lane = tid & 63, wave = tid >> 6;
  const size_t base = (size_t)blockIdx.x * 2048;
  float v[8]; load8(X + base + tid*8, v);
  float s = 0.f, s2 = 0.f;
  for (int j = 0; j < 8; ++j) { s += v[j]; s2 += v[j]*v[j]; }
  for (int m = 1; m < 64; m <<= 1) { s += __shfl_xor(s, m, 64); s2 += __shfl_xor(s2, m, 64); }
  if (lane == 0) { red[wave] = s; red[4 + wave] = s2; }
  __syncthreads();
  s  = red[0] + red[1] + red[2] + red[3];
  s2 = red[4] + red[5] + red[6] + red[7];
  const float mu = s * (1.f/2048.f);
  const float rstd = rsqrtf(s2 * (1.f/2048.f) - mu*mu + 1e-5f);
  float g[8], bb[8];
  load8(G + tid*8, g); load8(Bt + tid*8, bb);
  for (int j = 0; j < 8; ++j) buf[tid*8 + j] = (v[j] - mu) * rstd * g[j] + bb[j];
  __syncthreads();
  for (int h = 1; h < 2048; h <<= 1) {
    for (int p = 0; p < 4; ++p) {
      const int idx = p*256 + tid;
      const int i = ((idx & ~(h-1)) << 1) | (idx & (h-1));
      const float a = buf[i], c = buf[i + h];
      buf[i] = a + c; buf[i + h] = a - c;
    }
    __syncthreads();
  }
  float o[8];
  for (int j = 0; j < 8; ++j) o[j] = buf[tid*8 + j] * 0.02209708691207961f; // 1/sqrt(2048)
  *(uint4*)&O[base + tid*8] = pack8(o);
}

// ---------- in-place FWHT<N> on bf16 rows ----------
template<int N>
__global__ __launch_bounds__(256) void fwht_ip(u16* __restrict__ D) {
  __shared__ float buf[N];
  const int tid = threadIdx.x;
  const size_t base = (size_t)blockIdx.x * N;
  constexpr int V8 = N / (8*256);
  for (int i = 0; i < V8; ++i) {
    uint4 raw = *(const uint4*)&D[base + (i*256 + tid)*8];
    float v[8]; unpack8(raw, v);
    for (int j = 0; j < 8; ++j) buf[(i*256 + tid)*8 + j] = v[j];
  }
  __syncthreads();
  constexpr int PAIRS = N / 2 / 256;
  for (int h = 1; h < N; h <<= 1) {
    for (int p = 0; p < PAIRS; ++p) {
      const int idx = p*256 + tid;
      const int i = ((idx & ~(h-1)) << 1) | (idx & (h-1));
      const float a = buf[i], c = buf[i + h];
      buf[i] = a + c; buf[i + h] = a - c;
    }
    __syncthreads();
  }
  const float sc = rsqrtf((float)N);
  for (int i = 0; i < V8; ++i) {
    float v[8];
    for (int j = 0; j < 8; ++j) v[j] = buf[(i*256 + tid)*8 + j] * sc;
    *(uint4*)&D[base + (i*256 + tid)*8] = pack8(v);
  }
}

// ---------- 256x128 triple-buffered GEMM, 2 MFMA-phases per K-tile ----------
// (unchanged -- verified good; see journal)
__global__ __launch_bounds__(512, 1) void gemm256(
    const u16* __restrict__ A, const u16* __restrict__ Bw, const float* __restrict__ S,
    void* __restrict__ C, int ldc, int M, int N, int K,
    const float* __restrict__ bias, const float* __restrict__ resf,
    const u16* __restrict__ resb, int dogelu, int outf32)
{
  __shared__ alignas(16) u16 sA[3][256*64];
  __shared__ alignas(16) u16 sB[3][128*64];
  const int tid = threadIdx.x;
  const int lane = tid & 63, wave = tid >> 6;       // 8 waves
  const int quad = lane >> 4, l16 = lane & 15;
  const int wm = wave & 3, wn = wave >> 2;          // 4 M-waves x 2 N-waves
  const int nwg = gridDim.x * gridDim.y;
  int flat = blockIdx.y * gridDim.x + blockIdx.x;
  if ((nwg & 7) == 0) flat = (flat & 7) * (nwg >> 3) + (flat >> 3);
  const long tM = (long)(flat % gridDim.x) * 256;
  const long tN = (long)(flat / gridDim.x) * 128;

  const int rc = lane >> 3;
  const int cswz = ((lane & 7) ^ rc) * 8;
  const u16* Ab = A  + (size_t)(tM + rc) * K + cswz;
  const u16* Bb = Bw + (size_t)(tN + rc) * K + cswz;

  f32x4 acc[4][4] = {};
  const int ntk = K >> 6;

  auto stageA = [&](int buf, int k0, int i) {
    const int chunk = i*8 + wave;
    gload16(Ab + (size_t)(chunk*8)*K + k0, &sA[buf][chunk*512]);
  };
  auto stageB = [&](int buf, int k0, int i) {
    const int chunk = i*8 + wave;
    gload16(Bb + (size_t)(chunk*8)*K + k0, &sB[buf][chunk*512]);
  };

  stageA(0, 0, 0); stageA(0, 0, 1); stageA(0, 0, 2); stageA(0, 0, 3);
  stageB(0, 0, 0); stageB(0, 0, 1);
  if (ntk > 1) {
    stageA(1, 64, 0); stageA(1, 64, 1); stageA(1, 64, 2); stageA(1, 64, 3);
    stageB(1, 64, 0); stageB(1, 64, 1);
  }
  asm volatile("s_waitcnt vmcnt(6)" ::: "memory");   // tile 0 complete
  __builtin_amdgcn_s_barrier();
  __builtin_amdgcn_sched_barrier(0);

  for (int t = 0; t < ntk; ++t) {
    const int buf = t % 3, nb = (t + 2) % 3;
    const bool more = (t + 2) < ntk;
    const int k2 = (t + 2) << 6;
    bf16x8 af[4], bq[4];
#pragma unroll
    for (int ks = 0; ks < 2; ++ks) {
      const int oc = ks*4 + quad;
#pragma unroll
      for (int mt = 0; mt < 4; ++mt)
        af[mt] = *(const bf16x8*)&sA[buf][(wm*64 + mt*16 + l16)*64 + (oc ^ (l16 & 7))*8];
#pragma unroll
      for (int nt = 0; nt < 4; ++nt)
        bq[nt] = *(const bf16x8*)&sB[buf][(wn*64 + nt*16 + l16)*64 + (oc ^ (l16 & 7))*8];
      if (more) {
        if (ks == 0) { stageA(nb, k2, 0); stageA(nb, k2, 1); stageB(nb, k2, 0); }
        else         { stageA(nb, k2, 2); stageA(nb, k2, 3); stageB(nb, k2, 1); }
      }
      if (ks == 1 && t + 1 < ntk) {
        if (more) asm volatile("s_waitcnt vmcnt(6)" ::: "memory");
        else      asm volatile("s_waitcnt vmcnt(0)" ::: "memory");
      }
      __builtin_amdgcn_s_barrier();
      __builtin_amdgcn_sched_barrier(0);
      __builtin_amdgcn_s_setprio(1);
#pragma unroll
      for (int mt = 0; mt < 4; ++mt)
#pragma unroll
        for (int nt = 0; nt < 4; ++nt)
          acc[mt][nt] = __builtin_amdgcn_mfma_f32_16x16x32_bf16(af[mt], bq[nt], acc[mt][nt], 0, 0, 0);
      __builtin_amdgcn_s_setprio(0);
      __builtin_amdgcn_s_barrier();
      __builtin_amdgcn_sched_barrier(0);
    }
  }

#pragma unroll
  for (int in = 0; in < 4; ++in) {
    const long col = tN + wn*64 + in*16 + l16;
    const float sc = S[col];
    const float bv = bias ? bias[col] : 0.f;
#pragma unroll
    for (int im = 0; im < 4; ++im) {
      const long row0 = tM + wm*64 + im*16 + quad*4;
#pragma unroll
      for (int r = 0; r < 4; ++r) {
        float v = acc[im][in][r] * sc + bv;
        if (dogelu) v = 0.5f * v * (1.f + erff(v * 0.7071067811865475f));
        const size_t off = (size_t)(row0 + r)*ldc + col;
        if (resf) v += resf[off];
        if (resb) v += bf2f(resb[off]);
        if (outf32) ((float*)C)[off] = v;
        else        ((u16*)C)[off]   = f2bf(v);
      }
    }
  }
}

// ---------- fused MFMA attention: QKV packed [4096, 6144] bf16, O [4096, 2048] bf16 ----------
// REVERTED to the round-3 version (measured 170 µs, VGPR 128, WRITE 27 MB).
// Post-mortem of rounds 4-8: every swizzle/geometry "improvement" pushed the
// register allocator into scratch spill (WRITE 79-117 MB, FETCH 255-384 MB) --
// spill round-trips, not bank conflicts, dominated. This config is the only
// one with a near-clean allocation. Do not add address math here without
// re-checking VGPR_Count/WRITE_SIZE.
__global__ __launch_bounds__(256, 2) void attn_k(const u16* __restrict__ QKV, u16* __restrict__ O)
{
  __shared__ alignas(16) u16 sKV[16384];  // K tile [128][128], then V^T tile [d=128][kv=128]
  __shared__ alignas(16) u16 sP[16384];   // Q tile [128][128] at start, then per-wave P [32][128]
  const int tid = threadIdx.x;
  const int lane = tid & 63, wave = tid >> 6;
  const int quad = lane >> 4, l16 = lane & 15;
  const int qt = blockIdx.x;        // 0..7
  const int bh = blockIdx.y;        // 0..63
  const int b = bh >> 4, h = bh & 15;
  const size_t rb = (size_t)b * 1024;
  const u16* Qg = QKV + (rb + (size_t)qt*128)*6144 + h*128;
  const u16* Kg = QKV + rb*6144 + 2048 + h*128;
  const u16* Vg = QKV + rb*6144 + 4096 + h*128;

  for (int c = 0; c < 8; ++c) {
    const int chunk = c*4 + wave;        // 0..31, 1 KiB = 4 rows
    const int r = chunk*4 + quad;
    gload16(Qg + (size_t)r*6144 + l16*8, &sP[chunk*512]);
  }
  __syncthreads();
  bf16x8 aq[2][4];
  for (int im = 0; im < 2; ++im)
    for (int kk = 0; kk < 4; ++kk)
      aq[im][kk] = *(const bf16x8*)&sP[(wave*32 + im*16 + l16)*128 + kk*32 + quad*8];

  float mrun[2][4], lrun[2][4];
  f32x4 oacc[2][8] = {};
  for (int im = 0; im < 2; ++im)
    for (int r = 0; r < 4; ++r) { mrun[im][r] = -1e30f; lrun[im][r] = 0.f; }

  for (int kt = 0; kt < 8; ++kt) {
    __syncthreads();
    for (int c = 0; c < 8; ++c) {
      const int chunk = c*4 + wave;
      const int r = chunk*4 + quad;
      gload16(Kg + (size_t)(kt*128 + r)*6144 + l16*8, &sKV[chunk*512]);
    }
    __syncthreads();
    f32x4 sf[2][8] = {};
#pragma unroll
    for (int kk = 0; kk < 4; ++kk)
#pragma unroll
      for (int jn = 0; jn < 8; ++jn) {
        const bf16x8 bk = *(const bf16x8*)&sKV[(jn*16 + l16)*128 + kk*32 + quad*8];
        sf[0][jn] = __builtin_amdgcn_mfma_f32_16x16x32_bf16(aq[0][kk], bk, sf[0][jn], 0, 0, 0);
        sf[1][jn] = __builtin_amdgcn_mfma_f32_16x16x32_bf16(aq[1][kk], bk, sf[1][jn], 0, 0, 0);
      }
    const float scale = 0.08838834764831845f;   // 1/sqrt(128)
#pragma unroll
    for (int im = 0; im < 2; ++im)
#pragma unroll
      for (int r = 0; r < 4; ++r) {
        float mx = -1e30f;
        for (int jn = 0; jn < 8; ++jn) mx = fmaxf(mx, sf[im][jn][r] * scale);
        for (int m = 1; m < 16; m <<= 1) mx = fmaxf(mx, __shfl_xor(mx, m, 64));
        const float mold = mrun[im][r];
        const float mnew = fmaxf(mold, mx);
        const float alpha = __expf(mold - mnew);
        float ls = 0.f;
        for (int jn = 0; jn < 8; ++jn) {
          const float p = __expf(sf[im][jn][r] * scale - mnew);
          ls += p;
          sP[wave*4096 + (im*16 + quad*4 + r)*128 + jn*16 + l16] = f2bf(p);
        }
        for (int m = 1; m < 16; m <<= 1) ls += __shfl_xor(ls, m, 64);
        lrun[im][r] = lrun[im][r]*alpha + ls;
        mrun[im][r] = mnew;
        for (int od = 0; od < 8; ++od) oacc[im][od][r] *= alpha;
      }
    __syncthreads();
    for (int c = 0; c < 8; ++c) {
      const int chunk = c*256 + tid;       // 0..2047
      const int kv = chunk >> 4;
      const int db = (chunk & 15) * 8;
      const uint4 raw = *(const uint4*)(Vg + (size_t)(kt*128 + kv)*6144 + db);
      const u32 w0[4] = {raw.x, raw.y, raw.z, raw.w};
      for (int j = 0; j < 4; ++j) {
        sKV[(db + 2*j  )*128 + kv] = (u16)(w0[j] & 0xffff);
        sKV[(db + 2*j+1)*128 + kv] = (u16)(w0[j] >> 16);
      }
    }
    __syncthreads();
#pragma unroll
    for (int kk = 0; kk < 4; ++kk) {
      const bf16x8 ap0 = *(const bf16x8*)&sP[wave*4096 + (     l16)*128 + kk*32 + quad*8];
      const bf16x8 ap1 = *(const bf16x8*)&sP[wave*4096 + (16 + l16)*128 + kk*32 + quad*8];
#pragma unroll
      for (int od = 0; od < 8; ++od) {
        const bf16x8 bv = *(const bf16x8*)&sKV[(od*16 + l16)*128 + kk*32 + quad*8];
        oacc[0][od] = __builtin_amdgcn_mfma_f32_16x16x32_bf16(ap0, bv, oacc[0][od], 0, 0, 0);
        oacc[1][od] = __builtin_amdgcn_mfma_f32_16x16x32_bf16(ap1, bv, oacc[1][od], 0, 0, 0);
      }
    }
  }
  for (int im = 0; im < 2; ++im)
    for (int r = 0; r < 4; ++r) {
      const float inv = 1.f / lrun[im][r];
      const size_t row = rb + (size_t)qt*128 + wave*32 + im*16 + quad*4 + r;
      for (int od = 0; od < 8; ++od)
        O[row*2048 + h*128 + od*16 + l16] = f2bf(oacc[im][od][r] * inv);
    }
}

extern "C" void kernel_launch(void* const* d_in, const int* in_sizes, int n_in,
                              void* d_out, int out_size, void* d_ws, size_t ws_size,
                              hipStream_t stream) {
  const float* x    = (const float*)d_in[0];
  const float* ln1g = (const float*)d_in[1];
  const float* ln1b = (const float*)d_in[2];
  const float* ln2g = (const float*)d_in[3];
  const float* ln2b = (const float*)d_in[4];
  const int* Qq  = (const int*)d_in[5];  const float* sq  = (const float*)d_in[6];
  const int* Qk  = (const int*)d_in[7];  const float* sk  = (const float*)d_in[8];
  const int* Qv  = (const int*)d_in[9];  const float* sv  = (const float*)d_in[10];
  const int* Qo  = (const int*)d_in[11]; const float* so  = (const float*)d_in[12];
  const int* Qf1 = (const int*)d_in[13]; const float* sf1 = (const float*)d_in[14];
  const float* bf1 = (const float*)d_in[15];
  const int* Qf2 = (const int*)d_in[16]; const float* sf2 = (const float*)d_in[17];
  const float* bf2 = (const float*)d_in[18];

  // arena (u16 elems), 96 MiB, byte map:
  //   XH   [ 0,16) MiB : XH1 -> ATT -> XH2
  //   Wq   [16,40) MiB : QKV weights concat [6144,2048] bf16 (24 MiB)
  //   Wsl  [16,32) MiB : rotating weight slot (Qo 8 MiB, FF1 halves 16 MiB)
  //   QKV  [40,88) MiB : [4096,6144] bf16
  //   FF   [32,96) MiB : [4096,8192] bf16 (after attn; QKV dead)
  //   Wf2  [ 0,32) MiB : FF2 weight [2048,8192] bf16 (XH & Wsl dead by then)
  //   Scat [88, +24KiB): concat scales f32[6144]
  u16* XH   = (u16*)d_ws;
  u16* Wq   = XH + 8388608;
  u16* Wsl  = XH + 8388608;
  u16* QKVb = XH + 20971520;
  u16* FFb  = XH + 16777216;
  u16* Wf2  = XH;
  float* Scat = (float*)(XH + 46137344);
  float* Xout = (float*)d_out;
  if (ws_size < (size_t)100663296) return;   // guard (signals via poisoned d_out)

  // 1) LN1 + FWHT (f32 x -> bf16 XH1)
  ln_fwht_k<float><<<4096, 256, 0, stream>>>(x, ln1g, ln1b, XH);

  // 2) fused QKV projection: one N=6144 GEMM (concat weights + scales)
  cvt_k<<<2048, 256, 0, stream>>>(Qq, Wq);
  cvt_k<<<2048, 256, 0, stream>>>(Qk, Wq + 4194304);
  cvt_k<<<2048, 256, 0, stream>>>(Qv, Wq + 8388608);
  scat_k<<<24, 256, 0, stream>>>(sq, sk, sv, Scat);
  gemm256<<<dim3(16,48), 512, 0, stream>>>(XH, Wq, Scat, QKVb, 6144, 4096, 6144, 2048,
                                           nullptr, nullptr, nullptr, 0, 0);

  // 3) attention -> ATT (XH region)
  attn_k<<<dim3(8, 64), 256, 0, stream>>>(QKVb, XH);

  // 4) FWHT(2048) in-place on ATT
  fwht_ip<2048><<<4096, 256, 0, stream>>>(XH);

  // 5) O-proj + residual(x, f32) -> X1 = d_out (f32)
  cvt_k<<<2048, 256, 0, stream>>>(Qo, Wsl);
  gemm256<<<dim3(16,16), 512, 0, stream>>>(XH, Wsl, so, Xout, 2048, 4096, 2048, 2048,
                                           nullptr, x, nullptr, 0, 1);

  // 6) LN2 + FWHT: X1 (f32, in d_out) -> XH2
  ln_fwht_k<float><<<4096, 256, 0, stream>>>(Xout, ln2g, ln2b, XH);

  // 7) FF1 + bias + exact GELU -> FF (bf16), split along N (weight half fits Wsl)
  cvt_k<<<4096, 256, 0, stream>>>(Qf1, Wsl);
  gemm256<<<dim3(16,32), 512, 0, stream>>>(XH, Wsl, sf1,        FFb + 0,    8192, 4096, 4096, 2048,
                                           bf1,        nullptr, nullptr, 1, 0);
  cvt_k<<<4096, 256, 0, stream>>>(Qf1 + (size_t)4096*2048, Wsl);
  gemm256<<<dim3(16,32), 512, 0, stream>>>(XH, Wsl, sf1 + 4096, FFb + 4096, 8192, 4096, 4096, 2048,
                                           bf1 + 4096, nullptr, nullptr, 1, 0);

  // 8) FWHT(8192) in-place on FF
  fwht_ip<8192><<<4096, 256, 0, stream>>>(FFb);

  // 9) FF2 (unsplit, K=8192) + bias + residual(X1 in d_out) -> d_out (f32)
  cvt_k<<<8192, 256, 0, stream>>>(Qf2, Wf2);
  gemm256<<<dim3(16,16), 512, 0, stream>>>(FFb, Wf2, sf2, Xout, 2048, 4096, 2048, 8192,
                                           bf2, Xout, nullptr, 0, 1);
}